// Round 2
// 1954.777 us; speedup vs baseline: 1.5286x; 1.5286x over previous
//
#include <hip/hip_runtime.h>
#include <cstdint>

#define NN 300000
#define NE 600000
#define HD 128
#define NL 5
#define NG 8192
#define AVOC 128
#define BVOC 8
#define NAF 9
#define NBF 3
#define BN_EPS 1e-5f

#define SCAN_B 2048
#define SCAN_NB ((NN + SCAN_B - 1) / SCAN_B)   // 147

#define GBM 256
#define GBLK ((NN + GBM - 1) / GBM)            // 1172

typedef unsigned short u16;
typedef unsigned int u32;
typedef __attribute__((ext_vector_type(8))) short bf16x8;
typedef __attribute__((ext_vector_type(4))) float f32x4;

static __device__ __forceinline__ void atomAddF(float* p, float v) { unsafeAtomicAdd(p, v); }

static __device__ __forceinline__ float bf2f(u16 v) {
  union { u32 u; float f; } c; c.u = ((u32)v) << 16; return c.f;
}
static __device__ __forceinline__ u16 f2bf(float f) {
  union { float f; u32 u; } c; c.f = f;
  u32 u = c.u;
  return (u16)((u + 0x7FFFu + ((u >> 16) & 1u)) >> 16);  // RNE
}
static __device__ __forceinline__ u32 cvtpk(float a, float b) {
  u32 r;
  asm("v_cvt_pk_bf16_f32 %0, %1, %2" : "=v"(r) : "v"(a), "v"(b));
  return r;  // lo16 = bf16(a), hi16 = bf16(b), RNE
}
static __device__ __forceinline__ void unp8(uint4 p, float* v) {
  v[0] = bf2f((u16)(p.x & 0xffff)); v[1] = bf2f((u16)(p.x >> 16));
  v[2] = bf2f((u16)(p.y & 0xffff)); v[3] = bf2f((u16)(p.y >> 16));
  v[4] = bf2f((u16)(p.z & 0xffff)); v[5] = bf2f((u16)(p.z >> 16));
  v[6] = bf2f((u16)(p.w & 0xffff)); v[7] = bf2f((u16)(p.w >> 16));
}
static __device__ __forceinline__ uint4 pk8(const float* v) {
  uint4 p;
  p.x = ((u32)f2bf(v[1]) << 16) | f2bf(v[0]);
  p.y = ((u32)f2bf(v[3]) << 16) | f2bf(v[2]);
  p.z = ((u32)f2bf(v[5]) << 16) | f2bf(v[4]);
  p.w = ((u32)f2bf(v[7]) << 16) | f2bf(v[6]);
  return p;
}

// split fp32[8] -> hi bf16x8 + lo bf16x8  (hi+lo represents v to ~2^-17 rel)
static __device__ __forceinline__ void split8(const float* v, bf16x8& hi, bf16x8& lo) {
  union { u32 u[4]; bf16x8 h; } H, L;
  H.u[0] = cvtpk(v[0], v[1]); H.u[1] = cvtpk(v[2], v[3]);
  H.u[2] = cvtpk(v[4], v[5]); H.u[3] = cvtpk(v[6], v[7]);
  float r[8];
  r[0] = bf2f((u16)(H.u[0] & 0xffff)); r[1] = bf2f((u16)(H.u[0] >> 16));
  r[2] = bf2f((u16)(H.u[1] & 0xffff)); r[3] = bf2f((u16)(H.u[1] >> 16));
  r[4] = bf2f((u16)(H.u[2] & 0xffff)); r[5] = bf2f((u16)(H.u[2] >> 16));
  r[6] = bf2f((u16)(H.u[3] & 0xffff)); r[7] = bf2f((u16)(H.u[3] >> 16));
  L.u[0] = cvtpk(v[0] - r[0], v[1] - r[1]); L.u[1] = cvtpk(v[2] - r[2], v[3] - r[3]);
  L.u[2] = cvtpk(v[4] - r[4], v[5] - r[5]); L.u[3] = cvtpk(v[6] - r[6], v[7] - r[7]);
  hi = H.h; lo = L.h;
}

// ================= CSR construction =================
__global__ __launch_bounds__(256) void count_k(const int* __restrict__ ei,
    int* __restrict__ cnt_row, int* __restrict__ cnt_col) {
  int e = blockIdx.x * 256 + threadIdx.x;
  if (e >= NE) return;
  atomicAdd(&cnt_row[ei[e]], 1);
  atomicAdd(&cnt_col[ei[NE + e]], 1);
}

__global__ __launch_bounds__(256) void scan_block_k(int* __restrict__ P, int* __restrict__ bsum) {
  __shared__ int s[256];
  int b = blockIdx.x, t = threadIdx.x;
  int base = b * SCAN_B + t * 8;
  int v[8]; int ts = 0;
#pragma unroll
  for (int j = 0; j < 8; j++) { v[j] = (base + j < NN) ? P[base + j] : 0; ts += v[j]; }
  s[t] = ts;
  __syncthreads();
  for (int off = 1; off < 256; off <<= 1) {
    int tmp = 0;
    if (t >= off) tmp = s[t - off];
    __syncthreads();
    if (t >= off) s[t] += tmp;
    __syncthreads();
  }
  if (t == 255) bsum[b] = s[255];
  int run = (t == 0) ? 0 : s[t - 1];
#pragma unroll
  for (int j = 0; j < 8; j++) {
    if (base + j < NN) P[base + j] = run;
    run += v[j];
  }
}

__global__ __launch_bounds__(256) void scan_tops_k(int* __restrict__ bsum, int* __restrict__ totOut) {
  __shared__ int s[256];
  int t = threadIdx.x;
  s[t] = (t < SCAN_NB) ? bsum[t] : 0;
  __syncthreads();
  for (int off = 1; off < 256; off <<= 1) {
    int tmp = 0;
    if (t >= off) tmp = s[t - off];
    __syncthreads();
    if (t >= off) s[t] += tmp;
    __syncthreads();
  }
  if (t < SCAN_NB) bsum[t] = (t == 0) ? 0 : s[t - 1];
  if (t == 255) *totOut = s[255];
}

__global__ __launch_bounds__(256) void scan_add_k(int* __restrict__ P, const int* __restrict__ bsum) {
  int b = blockIdx.x, t = threadIdx.x;
  int off = bsum[b];
  int base = b * SCAN_B + t * 8;
#pragma unroll
  for (int j = 0; j < 8; j++)
    if (base + j < NN) P[base + j] += off;
}

__global__ __launch_bounds__(256) void fill_k(const int* __restrict__ ei,
    const int* __restrict__ ptr_row, const int* __restrict__ ptr_col,
    int* __restrict__ fillr, int* __restrict__ fillc,
    int* __restrict__ adj_row, int* __restrict__ adj_col) {
  int e = blockIdx.x * 256 + threadIdx.x;
  if (e >= NE) return;
  int r = ei[e], c = ei[NE + e];
  int p1 = atomicAdd(&fillr[r], 1);
  adj_row[ptr_row[r] + p1] = e;
  int p2 = atomicAdd(&fillc[c], 1);
  adj_col[ptr_col[c] + p2] = r;
}

__global__ __launch_bounds__(256) void inv_k(const int* __restrict__ ptr_row, float* __restrict__ inv) {
  int n = blockIdx.x * 256 + threadIdx.x;
  if (n < NN) inv[n] = 1.0f / ((float)(ptr_row[n + 1] - ptr_row[n]) + 1.0f);
}

__global__ __launch_bounds__(256) void gp_k(const int* __restrict__ batch, int* __restrict__ gp) {
  int g = blockIdx.x * 256 + threadIdx.x;
  if (g > NG) return;
  int lo = 0, hi = NN;
  while (lo < hi) { int mid = (lo + hi) >> 1; if (batch[mid] < g) lo = mid + 1; else hi = mid; }
  gp[g] = lo;
}

// W split/transpose: Wt[m][c][k] = bf16_hi/lo of W_m[k][c];  m<5 -> w1[m], else w2[m-5]
__global__ __launch_bounds__(256) void wsplit_k(const float* __restrict__ w1,
    const float* __restrict__ w2, u16* __restrict__ Wt_hi, u16* __restrict__ Wt_lo) {
  int m = blockIdx.x;
  const float* W = (m < NL) ? (w1 + (size_t)m * HD * HD) : (w2 + (size_t)(m - NL) * HD * HD);
  int t = threadIdx.x;
  for (int p = 0; p < 64; p++) {
    int o = p * 256 + t;            // linear over [c][k]
    int c = o >> 7, k = o & 127;
    float w = W[k * HD + c];
    u16 hi = f2bf(w);
    float lo = w - bf2f(hi);
    Wt_hi[(size_t)m * HD * HD + o] = hi;
    Wt_lo[(size_t)m * HD * HD + o] = f2bf(lo);
  }
}

// ================= model kernels =================
__global__ __launch_bounds__(256) void atom_encoder_k(const int* __restrict__ x,
    const float* __restrict__ emb, u16* __restrict__ A) {
  int gid = blockIdx.x * 256 + threadIdx.x;
  if (gid >= NN * 16) return;
  int n = gid >> 4, c8 = gid & 15;
  float acc[8] = {0.f, 0.f, 0.f, 0.f, 0.f, 0.f, 0.f, 0.f};
#pragma unroll
  for (int f = 0; f < NAF; f++) {
    int v = x[n * NAF + f];
    const float* e = emb + ((size_t)(f * AVOC + v)) * HD + c8 * 8;
    float4 e0 = *(const float4*)e;
    float4 e1 = *(const float4*)(e + 4);
    acc[0] += e0.x; acc[1] += e0.y; acc[2] += e0.z; acc[3] += e0.w;
    acc[4] += e1.x; acc[5] += e1.y; acc[6] += e1.z; acc[7] += e1.w;
  }
  *(uint4*)(A + (size_t)n * HD + c8 * 8) = pk8(acc);
}

__global__ __launch_bounds__(256) void bond_hin_k(const int* __restrict__ ea,
    const float* __restrict__ be, const int* __restrict__ ptr_row,
    const int* __restrict__ adj_row, const float* __restrict__ inv,
    u16* __restrict__ A) {
  int t = threadIdx.x;
  int n = blockIdx.x * 16 + (t >> 4);
  int c8 = t & 15;
  if (n >= NN) return;
  int beg = ptr_row[n], end = ptr_row[n + 1];
  float acc[8] = {0.f, 0.f, 0.f, 0.f, 0.f, 0.f, 0.f, 0.f};
  for (int i = beg; i < end; i++) {
    int e = adj_row[i];
    int a0 = ea[e * 3 + 0], a1 = ea[e * 3 + 1], a2 = ea[e * 3 + 2];
    const float* p0 = be + (size_t)a0 * HD + c8 * 8;
    const float* p1 = be + (size_t)(BVOC + a1) * HD + c8 * 8;
    const float* p2 = be + (size_t)(2 * BVOC + a2) * HD + c8 * 8;
    float4 x0 = *(const float4*)p0, x1 = *(const float4*)(p0 + 4);
    float4 y0 = *(const float4*)p1, y1 = *(const float4*)(p1 + 4);
    float4 z0 = *(const float4*)p2, z1 = *(const float4*)(p2 + 4);
    acc[0] += x0.x + y0.x + z0.x; acc[1] += x0.y + y0.y + z0.y;
    acc[2] += x0.z + y0.z + z0.z; acc[3] += x0.w + y0.w + z0.w;
    acc[4] += x1.x + y1.x + z1.x; acc[5] += x1.y + y1.y + z1.y;
    acc[6] += x1.z + y1.z + z1.z; acc[7] += x1.w + y1.w + z1.w;
  }
  float iv = inv[n];
  uint4 pa = *(const uint4*)(A + (size_t)n * HD + c8 * 8);
  float h[8]; unp8(pa, h);
#pragma unroll
  for (int j = 0; j < 8; j++) h[j] = fmaf(acc[j], iv, h[j]);
  *(uint4*)(A + (size_t)n * HD + c8 * 8) = pk8(h);
}

// z = (1+eps)*h_in[n] + sum_{in-edges(col)} h_in[src]  -> B (fp32)   [round-0 dataflow]
__global__ __launch_bounds__(256) void aggr_z_k(const int* __restrict__ ptr_col,
    const int* __restrict__ adj_col, const u16* __restrict__ A,
    float* __restrict__ B, const float* __restrict__ eps, int l) {
  int t = threadIdx.x;
  int n = blockIdx.x * 16 + (t >> 4);
  int c8 = t & 15;
  if (n >= NN) return;
  float s = 1.0f + eps[l];
  uint4 pa = *(const uint4*)(A + (size_t)n * HD + c8 * 8);
  float z[8]; unp8(pa, z);
#pragma unroll
  for (int j = 0; j < 8; j++) z[j] *= s;
  int beg = ptr_col[n], end = ptr_col[n + 1];
  for (int i = beg; i < end; i++) {
    int src = adj_col[i];
    uint4 ps = *(const uint4*)(A + (size_t)src * HD + c8 * 8);
    float v[8]; unp8(ps, v);
#pragma unroll
    for (int j = 0; j < 8; j++) z[j] += v[j];
  }
  float* bp = B + (size_t)n * HD + c8 * 8;
  *(float4*)bp = make_float4(z[0], z[1], z[2], z[3]);
  *(float4*)(bp + 4) = make_float4(z[4], z[5], z[6], z[7]);
}

// ---------------- MFMA GEMM, fp32-grade via split operands ----------------
// 512 threads = 8 waves; block tile 256 rows; wave tile 32x128; K=128 in one pass.
// Only W lives in LDS (64 KB -> 2 blocks/CU). A rows are read per-wave straight from
// global into registers and split hi/lo there; no barrier inside the K loop.
// FUSE=false: A fp32 in, C bf16 out (gemm1).  FUSE=true: A bf16 + BN1/relu, C fp32 out (gemm2).
template<bool FUSE>
__global__ __launch_bounds__(512, 4) void gemm_mfma_k(
    const void* __restrict__ Ain, const u16* __restrict__ Whi, const u16* __restrict__ Wlo,
    const float* __restrict__ bias, void* __restrict__ Cout,
    float* __restrict__ stats, const float* __restrict__ ss) {
  __shared__ u16 sW[2 * HD * HD];     // 64 KB: hi then lo, [col][k], XOR-swizzled
  const int tid = threadIdx.x;

#pragma unroll
  for (int p = 0; p < 4; p++) {
    int idx = tid + p * 512;                    // 2048 x 16B chunks per plane
    int col = idx >> 4, k16 = idx & 15;
    uint4 vh = *(const uint4*)(Whi + idx * 8);
    uint4 vl = *(const uint4*)(Wlo + idx * 8);
    int so = (col << 7) + ((k16 << 3) ^ ((col & 7) << 3));
    *(uint4*)(sW + so) = vh;
    *(uint4*)(sW + HD * HD + so) = vl;
  }
  __syncthreads();

  const int l = tid & 63, w = tid >> 6;
  const int lr = l & 15, lk = l >> 4;
  const int rw = blockIdx.x * GBM + w * 32;     // this wave's first row
  f32x4 acc[2][8];
#pragma unroll
  for (int i = 0; i < 2; i++)
#pragma unroll
    for (int j = 0; j < 8; j++) acc[i][j] = (f32x4){0.f, 0.f, 0.f, 0.f};

#pragma unroll
  for (int ks = 0; ks < 4; ks++) {
    const int kb = ks * 32 + lk * 8;            // this lane's K offset (elems)
    bf16x8 ah[2], al[2];
#pragma unroll
    for (int i = 0; i < 2; i++) {
      int gr = rw + i * 16 + lr;
      float v[8];
      if constexpr (FUSE) {
        uint4 p = make_uint4(0u, 0u, 0u, 0u);
        if (gr < NN) p = *(const uint4*)((const u16*)Ain + (size_t)gr * HD + kb);
        unp8(p, v);
#pragma unroll
        for (int j = 0; j < 8; j++)
          v[j] = fmaxf(fmaf(v[j], ss[kb + j], ss[HD + kb + j]), 0.f);
      } else {
        float4 a0 = make_float4(0.f, 0.f, 0.f, 0.f), a1 = a0;
        if (gr < NN) {
          const float* ap = (const float*)Ain + (size_t)gr * HD + kb;
          a0 = *(const float4*)ap; a1 = *(const float4*)(ap + 4);
        }
        v[0] = a0.x; v[1] = a0.y; v[2] = a0.z; v[3] = a0.w;
        v[4] = a1.x; v[5] = a1.y; v[6] = a1.z; v[7] = a1.w;
      }
      split8(v, ah[i], al[i]);
    }
#pragma unroll
    for (int jt = 0; jt < 8; jt++) {
      int col = jt * 16 + lr;
      int so = (col << 7) + (kb ^ ((col & 7) << 3));
      bf16x8 bh = *(const bf16x8*)(sW + so);
      bf16x8 bl = *(const bf16x8*)(sW + HD * HD + so);
#pragma unroll
      for (int i = 0; i < 2; i++) {
        acc[i][jt] = __builtin_amdgcn_mfma_f32_16x16x32_bf16(ah[i], bh, acc[i][jt], 0, 0, 0);
        acc[i][jt] = __builtin_amdgcn_mfma_f32_16x16x32_bf16(al[i], bh, acc[i][jt], 0, 0, 0);
        acc[i][jt] = __builtin_amdgcn_mfma_f32_16x16x32_bf16(ah[i], bl, acc[i][jt], 0, 0, 0);
      }
    }
  }

  // ---- epilogue: +bias, BN stats (fp32, pre-rounding), stores ----
  // D layout (m89): col = lane&15 within 16-tile, row = (lane>>4)*4 + reg
  float bb[8];
#pragma unroll
  for (int jt = 0; jt < 8; jt++) bb[jt] = bias[jt * 16 + lr];
  float cs[8], cq[8];
#pragma unroll
  for (int jt = 0; jt < 8; jt++) { cs[jt] = 0.f; cq[jt] = 0.f; }
#pragma unroll
  for (int i = 0; i < 2; i++)
#pragma unroll
    for (int j = 0; j < 4; j++) {
      int gr = rw + i * 16 + lk * 4 + j;
      bool ok = gr < NN;
#pragma unroll
      for (int jt = 0; jt < 8; jt++) {
        float o = acc[i][jt][j] + bb[jt];
        if (ok) { cs[jt] += o; cq[jt] += o * o; }
        if constexpr (FUSE) {
          if (ok) *((float*)Cout + (size_t)gr * HD + jt * 16 + lr) = o;
        } else {
          float on = __shfl_xor(o, 1);          // partner col (same row)
          u32 pw = cvtpk(o, on);
          if (ok && !(l & 1))
            *(u32*)((u16*)Cout + (size_t)gr * HD + jt * 16 + lr) = pw;
        }
      }
    }
#pragma unroll
  for (int jt = 0; jt < 8; jt++) {
    cs[jt] += __shfl_xor(cs[jt], 16); cs[jt] += __shfl_xor(cs[jt], 32);
    cq[jt] += __shfl_xor(cq[jt], 16); cq[jt] += __shfl_xor(cq[jt], 32);
  }
  __syncthreads();                              // all sW reads done; reuse as scratch
  float* sS = (float*)sW;                       // [8][128] sums + [8][128] sumsq
  if (lk == 0) {
#pragma unroll
    for (int jt = 0; jt < 8; jt++) {
      sS[w * HD + jt * 16 + lr] = cs[jt];
      sS[1024 + w * HD + jt * 16 + lr] = cq[jt];
    }
  }
  __syncthreads();
  if (tid < HD) {
    float s = 0.f, q = 0.f;
#pragma unroll
    for (int g = 0; g < 8; g++) { s += sS[g * HD + tid]; q += sS[1024 + g * HD + tid]; }
    atomAddF(&stats[tid], s);
    atomAddF(&stats[HD + tid], q);
  }
}

__global__ __launch_bounds__(128) void scale_shift_k(float* __restrict__ stats,
    const float* __restrict__ g, const float* __restrict__ b) {
  int c = threadIdx.x;
  float mean = stats[c] * (1.0f / NN);
  float var = stats[HD + c] * (1.0f / NN) - mean * mean;
  float sc = g[c] * rsqrtf(var + BN_EPS);
  stats[256 + c] = sc;
  stats[384 + c] = fmaf(-mean, sc, b[c]);
}

// BN apply on B (fp32) -> A (bf16) (+relu)   [round-0 dataflow]
__global__ __launch_bounds__(256) void bn_apply_k(const float* __restrict__ Bin,
    u16* __restrict__ A, const float* __restrict__ ss, int relu) {
  int gid = blockIdx.x * 256 + threadIdx.x;
  if (gid >= NN * 16) return;
  int n = gid >> 4, c8 = gid & 15;
  const float* bp = Bin + (size_t)n * HD + c8 * 8;
  float4 b0 = *(const float4*)bp;
  float4 b1 = *(const float4*)(bp + 4);
  float v[8] = {b0.x, b0.y, b0.z, b0.w, b1.x, b1.y, b1.z, b1.w};
#pragma unroll
  for (int j = 0; j < 8; j++) {
    v[j] = fmaf(v[j], ss[c8 * 8 + j], ss[128 + c8 * 8 + j]);
    if (relu) v[j] = fmaxf(v[j], 0.f);
  }
  *(uint4*)(A + (size_t)n * HD + c8 * 8) = pk8(v);
}

// fused global_add_pool + 2-layer MLP head; one block per graph
__global__ __launch_bounds__(128) void pool_final_k(const u16* __restrict__ A,
    const int* __restrict__ gp, const float* __restrict__ cw1,
    const float* __restrict__ cb1, const float* __restrict__ cw2,
    const float* __restrict__ cb2, float* __restrict__ out) {
  __shared__ float sp[128];
  __shared__ float sh[128];
  int g = blockIdx.x, t = threadIdx.x;
  int beg = gp[g], end = gp[g + 1];
  float acc = 0.f;
  for (int n = beg; n < end; n++) acc += bf2f(A[(size_t)n * HD + t]);
  sp[t] = acc;
  __syncthreads();
  float h1 = cb1[t];
#pragma unroll
  for (int k = 0; k < HD; k++) h1 = fmaf(sp[k], cw1[k * HD + t], h1);
  h1 = fmaxf(h1, 0.f);
  sh[t] = h1 * cw2[t];
  __syncthreads();
  for (int s = 64; s >= 1; s >>= 1) {
    if (t < s) sh[t] += sh[t + s];
    __syncthreads();
  }
  if (t == 0) out[g] = sh[0] + cb2[0];
}

extern "C" void kernel_launch(void* const* d_in, const int* in_sizes, int n_in,
                              void* d_out, int out_size, void* d_ws, size_t ws_size,
                              hipStream_t stream) {
  const int*   x        = (const int*)d_in[0];
  const int*   ei       = (const int*)d_in[1];
  const int*   ea       = (const int*)d_in[2];
  const int*   batch    = (const int*)d_in[3];
  const float* atom_emb = (const float*)d_in[4];
  const float* bond_emb = (const float*)d_in[5];
  const float* eps      = (const float*)d_in[6];
  const float* w1       = (const float*)d_in[7];
  const float* b1       = (const float*)d_in[8];
  const float* bn1_g    = (const float*)d_in[9];
  const float* bn1_b    = (const float*)d_in[10];
  const float* w2       = (const float*)d_in[11];
  const float* b2       = (const float*)d_in[12];
  const float* bn_g     = (const float*)d_in[13];
  const float* bn_b     = (const float*)d_in[14];
  const float* cw1      = (const float*)d_in[15];
  const float* cb1      = (const float*)d_in[16];
  const float* cw2      = (const float*)d_in[17];
  const float* cb2      = (const float*)d_in[18];
  float* out = (float*)d_out;

  const size_t NH = (size_t)NN * HD;
  float* ws = (float*)d_ws;
  float* stats   = ws;                               // 5*1024 floats
  int*   ptr_row = (int*)(ws + 5 * 1024);            // NN+1
  int*   ptr_col = ptr_row + (NN + 1);               // NN+1
  int*   adj_row = ptr_col + (NN + 1);               // NE
  int*   adj_col = adj_row + NE;                     // NE
  int*   gp      = adj_col + NE;                     // NG+1
  float* inv     = (float*)(gp + (NG + 1));          // NN
  size_t off = 5 * 1024 + 2 * (size_t)(NN + 1) + 2 * (size_t)NE + (NG + 1) + NN;
  off = (off + 3) & ~(size_t)3;                      // 16B align
  float* B = ws + off;                               // NH fp32
  u16*   A = (u16*)(B + NH);                         // NH bf16
  u16*   Wt_hi = A + NH;                             // 10 * 128*128 bf16
  u16*   Wt_lo = Wt_hi + 10 * HD * HD;               // 10 * 128*128 bf16
  // setup-only temps aliased into B (B first written by aggr_z in layer 0)
  int* fillr = (int*)B;
  int* fillc = fillr + NN;
  int* bsums = fillc + NN;                           // SCAN_NB ints

  const int nb_n16  = (int)(((size_t)NN * 16 + 255) / 256);  // 18750
  const int nb_node = (NN + 15) / 16;                        // 18750
  const int nb_e    = (NE + 255) / 256;                      // 2344

  // ---- setup: CSR build + encoder + weight split + graph offsets ----
  hipMemsetAsync(stats, 0, 5 * 1024 * sizeof(float), stream);
  hipMemsetAsync(ptr_row, 0, 2 * (NN + 1) * sizeof(int), stream);
  hipMemsetAsync(fillr, 0, 2 * NN * sizeof(int), stream);

  count_k<<<nb_e, 256, 0, stream>>>(ei, ptr_row, ptr_col);
  scan_block_k<<<SCAN_NB, 256, 0, stream>>>(ptr_row, bsums);
  scan_tops_k<<<1, 256, 0, stream>>>(bsums, &ptr_row[NN]);
  scan_add_k<<<SCAN_NB, 256, 0, stream>>>(ptr_row, bsums);
  scan_block_k<<<SCAN_NB, 256, 0, stream>>>(ptr_col, bsums);
  scan_tops_k<<<1, 256, 0, stream>>>(bsums, &ptr_col[NN]);
  scan_add_k<<<SCAN_NB, 256, 0, stream>>>(ptr_col, bsums);
  inv_k<<<(NN + 255) / 256, 256, 0, stream>>>(ptr_row, inv);
  fill_k<<<nb_e, 256, 0, stream>>>(ei, ptr_row, ptr_col, fillr, fillc, adj_row, adj_col);
  wsplit_k<<<2 * NL, 256, 0, stream>>>(w1, w2, Wt_hi, Wt_lo);
  atom_encoder_k<<<nb_n16, 256, 0, stream>>>(x, atom_emb, A);
  gp_k<<<(NG + 1 + 255) / 256, 256, 0, stream>>>(batch, gp);

  // ---- layers ----
  for (int l = 0; l < NL; l++) {
    const float* be = bond_emb + (size_t)l * NBF * BVOC * HD;
    float* st = stats + (size_t)l * 1024;
    bond_hin_k<<<nb_node, 256, 0, stream>>>(ea, be, ptr_row, adj_row, inv, A);
    aggr_z_k<<<nb_node, 256, 0, stream>>>(ptr_col, adj_col, A, B, eps, l);
    gemm_mfma_k<false><<<GBLK, 512, 0, stream>>>(
        B, Wt_hi + (size_t)l * HD * HD, Wt_lo + (size_t)l * HD * HD,
        b1 + (size_t)l * HD, A, st, nullptr);
    scale_shift_k<<<1, 128, 0, stream>>>(st, bn1_g + (size_t)l * HD, bn1_b + (size_t)l * HD);
    gemm_mfma_k<true><<<GBLK, 512, 0, stream>>>(
        A, Wt_hi + (size_t)(NL + l) * HD * HD, Wt_lo + (size_t)(NL + l) * HD * HD,
        b2 + (size_t)l * HD, B, st + 512, st + 256);
    scale_shift_k<<<1, 128, 0, stream>>>(st + 512, bn_g + (size_t)l * HD, bn_b + (size_t)l * HD);
    bn_apply_k<<<nb_n16, 256, 0, stream>>>(B, A, st + 768, (l < NL - 1) ? 1 : 0);
  }

  // ---- pooled head ----
  pool_final_k<<<NG, 128, 0, stream>>>(A, gp, cw1, cb1, cw2, cb2, out);
}

// Round 3
// 1850.586 us; speedup vs baseline: 1.6146x; 1.0563x over previous
//
#include <hip/hip_runtime.h>
#include <cstdint>

#define NN 300000
#define NE 600000
#define HD 128
#define NL 5
#define NG 8192
#define AVOC 128
#define BVOC 8
#define NAF 9
#define NBF 3
#define BN_EPS 1e-5f

#define SCAN_B 2048
#define SCAN_NB ((NN + SCAN_B - 1) / SCAN_B)   // 147

#define GBM 256
#define GBLK ((NN + GBM - 1) / GBM)            // 1172

typedef unsigned short u16;
typedef unsigned int u32;
typedef __attribute__((ext_vector_type(8))) short bf16x8;
typedef __attribute__((ext_vector_type(4))) float f32x4;

static __device__ __forceinline__ void atomAddF(float* p, float v) { unsafeAtomicAdd(p, v); }

static __device__ __forceinline__ float bf2f(u16 v) {
  union { u32 u; float f; } c; c.u = ((u32)v) << 16; return c.f;
}
static __device__ __forceinline__ u16 f2bf(float f) {
  union { float f; u32 u; } c; c.f = f;
  u32 u = c.u;
  return (u16)((u + 0x7FFFu + ((u >> 16) & 1u)) >> 16);  // RNE
}
static __device__ __forceinline__ u32 cvtpk(float a, float b) {
  u32 r;
  asm("v_cvt_pk_bf16_f32 %0, %1, %2" : "=v"(r) : "v"(a), "v"(b));
  return r;  // lo16 = bf16(a), hi16 = bf16(b), RNE
}
static __device__ __forceinline__ void unp8(uint4 p, float* v) {
  v[0] = bf2f((u16)(p.x & 0xffff)); v[1] = bf2f((u16)(p.x >> 16));
  v[2] = bf2f((u16)(p.y & 0xffff)); v[3] = bf2f((u16)(p.y >> 16));
  v[4] = bf2f((u16)(p.z & 0xffff)); v[5] = bf2f((u16)(p.z >> 16));
  v[6] = bf2f((u16)(p.w & 0xffff)); v[7] = bf2f((u16)(p.w >> 16));
}
static __device__ __forceinline__ uint4 pk8(const float* v) {
  uint4 p;
  p.x = ((u32)f2bf(v[1]) << 16) | f2bf(v[0]);
  p.y = ((u32)f2bf(v[3]) << 16) | f2bf(v[2]);
  p.z = ((u32)f2bf(v[5]) << 16) | f2bf(v[4]);
  p.w = ((u32)f2bf(v[7]) << 16) | f2bf(v[6]);
  return p;
}

// split fp32[8] -> hi bf16x8 + lo bf16x8  (hi+lo represents v to ~2^-17 rel)
static __device__ __forceinline__ void split8(const float* v, bf16x8& hi, bf16x8& lo) {
  union { u32 u[4]; bf16x8 h; } H, L;
  H.u[0] = cvtpk(v[0], v[1]); H.u[1] = cvtpk(v[2], v[3]);
  H.u[2] = cvtpk(v[4], v[5]); H.u[3] = cvtpk(v[6], v[7]);
  float r[8];
  r[0] = bf2f((u16)(H.u[0] & 0xffff)); r[1] = bf2f((u16)(H.u[0] >> 16));
  r[2] = bf2f((u16)(H.u[1] & 0xffff)); r[3] = bf2f((u16)(H.u[1] >> 16));
  r[4] = bf2f((u16)(H.u[2] & 0xffff)); r[5] = bf2f((u16)(H.u[2] >> 16));
  r[6] = bf2f((u16)(H.u[3] & 0xffff)); r[7] = bf2f((u16)(H.u[3] >> 16));
  L.u[0] = cvtpk(v[0] - r[0], v[1] - r[1]); L.u[1] = cvtpk(v[2] - r[2], v[3] - r[3]);
  L.u[2] = cvtpk(v[4] - r[4], v[5] - r[5]); L.u[3] = cvtpk(v[6] - r[6], v[7] - r[7]);
  hi = H.h; lo = L.h;
}

// ================= CSR construction =================
__global__ __launch_bounds__(256) void count_k(const int* __restrict__ ei,
    int* __restrict__ cnt_row, int* __restrict__ cnt_col) {
  int e = blockIdx.x * 256 + threadIdx.x;
  if (e >= NE) return;
  atomicAdd(&cnt_row[ei[e]], 1);
  atomicAdd(&cnt_col[ei[NE + e]], 1);
}

__global__ __launch_bounds__(256) void scan_block_k(int* __restrict__ P, int* __restrict__ bsum) {
  __shared__ int s[256];
  int b = blockIdx.x, t = threadIdx.x;
  int base = b * SCAN_B + t * 8;
  int v[8]; int ts = 0;
#pragma unroll
  for (int j = 0; j < 8; j++) { v[j] = (base + j < NN) ? P[base + j] : 0; ts += v[j]; }
  s[t] = ts;
  __syncthreads();
  for (int off = 1; off < 256; off <<= 1) {
    int tmp = 0;
    if (t >= off) tmp = s[t - off];
    __syncthreads();
    if (t >= off) s[t] += tmp;
    __syncthreads();
  }
  if (t == 255) bsum[b] = s[255];
  int run = (t == 0) ? 0 : s[t - 1];
#pragma unroll
  for (int j = 0; j < 8; j++) {
    if (base + j < NN) P[base + j] = run;
    run += v[j];
  }
}

__global__ __launch_bounds__(256) void scan_tops_k(int* __restrict__ bsum, int* __restrict__ totOut) {
  __shared__ int s[256];
  int t = threadIdx.x;
  s[t] = (t < SCAN_NB) ? bsum[t] : 0;
  __syncthreads();
  for (int off = 1; off < 256; off <<= 1) {
    int tmp = 0;
    if (t >= off) tmp = s[t - off];
    __syncthreads();
    if (t >= off) s[t] += tmp;
    __syncthreads();
  }
  if (t < SCAN_NB) bsum[t] = (t == 0) ? 0 : s[t - 1];
  if (t == 255) *totOut = s[255];
}

__global__ __launch_bounds__(256) void scan_add_k(int* __restrict__ P, const int* __restrict__ bsum) {
  int b = blockIdx.x, t = threadIdx.x;
  int off = bsum[b];
  int base = b * SCAN_B + t * 8;
#pragma unroll
  for (int j = 0; j < 8; j++)
    if (base + j < NN) P[base + j] += off;
}

__global__ __launch_bounds__(256) void fill_k(const int* __restrict__ ei,
    const int* __restrict__ ptr_row, const int* __restrict__ ptr_col,
    int* __restrict__ fillr, int* __restrict__ fillc,
    int* __restrict__ adj_row, int* __restrict__ adj_col) {
  int e = blockIdx.x * 256 + threadIdx.x;
  if (e >= NE) return;
  int r = ei[e], c = ei[NE + e];
  int p1 = atomicAdd(&fillr[r], 1);
  adj_row[ptr_row[r] + p1] = e;
  int p2 = atomicAdd(&fillc[c], 1);
  adj_col[ptr_col[c] + p2] = r;
}

__global__ __launch_bounds__(256) void inv_k(const int* __restrict__ ptr_row, float* __restrict__ inv) {
  int n = blockIdx.x * 256 + threadIdx.x;
  if (n < NN) inv[n] = 1.0f / ((float)(ptr_row[n + 1] - ptr_row[n]) + 1.0f);
}

__global__ __launch_bounds__(256) void gp_k(const int* __restrict__ batch, int* __restrict__ gp) {
  int g = blockIdx.x * 256 + threadIdx.x;
  if (g > NG) return;
  int lo = 0, hi = NN;
  while (lo < hi) { int mid = (lo + hi) >> 1; if (batch[mid] < g) lo = mid + 1; else hi = mid; }
  gp[g] = lo;
}

// W split/transpose: Wt[m][c][k] = bf16_hi/lo of W_m[k][c];  m<5 -> w1[m], else w2[m-5]
__global__ __launch_bounds__(256) void wsplit_k(const float* __restrict__ w1,
    const float* __restrict__ w2, u16* __restrict__ Wt_hi, u16* __restrict__ Wt_lo) {
  int m = blockIdx.x;
  const float* W = (m < NL) ? (w1 + (size_t)m * HD * HD) : (w2 + (size_t)(m - NL) * HD * HD);
  int t = threadIdx.x;
  for (int p = 0; p < 64; p++) {
    int o = p * 256 + t;            // linear over [c][k]
    int c = o >> 7, k = o & 127;
    float w = W[k * HD + c];
    u16 hi = f2bf(w);
    float lo = w - bf2f(hi);
    Wt_hi[(size_t)m * HD * HD + o] = hi;
    Wt_lo[(size_t)m * HD * HD + o] = f2bf(lo);
  }
}

// ================= model kernels =================

// bond + h_in, fused with either the atom encoder (ENC, layer 0) or the
// previous layer's BN+relu (from Z2 bf16 + ss).  h_in -> A (bf16).
template<bool ENC>
__global__ __launch_bounds__(256) void bond_k(const int* __restrict__ ea,
    const float* __restrict__ be, const int* __restrict__ ptr_row,
    const int* __restrict__ adj_row, const float* __restrict__ inv,
    const int* __restrict__ x, const float* __restrict__ emb,
    const u16* __restrict__ Z2, const float* __restrict__ ss,
    u16* __restrict__ A) {
  __shared__ int sx[16 * NAF];
  int t = threadIdx.x;
  int nb = blockIdx.x * 16;
  int n = nb + (t >> 4);
  int c8 = t & 15;
  if constexpr (ENC) {
    if (t < 16 * NAF && nb * NAF + t < NN * NAF) sx[t] = x[nb * NAF + t];
    __syncthreads();
  }
  if (n >= NN) return;
  float h[8];
  if constexpr (ENC) {
#pragma unroll
    for (int j = 0; j < 8; j++) h[j] = 0.f;
#pragma unroll
    for (int f = 0; f < NAF; f++) {
      int v = sx[(t >> 4) * NAF + f];
      const float* e = emb + ((size_t)(f * AVOC + v)) * HD + c8 * 8;
      float4 e0 = *(const float4*)e;
      float4 e1 = *(const float4*)(e + 4);
      h[0] += e0.x; h[1] += e0.y; h[2] += e0.z; h[3] += e0.w;
      h[4] += e1.x; h[5] += e1.y; h[6] += e1.z; h[7] += e1.w;
    }
  } else {
    uint4 p = *(const uint4*)(Z2 + (size_t)n * HD + c8 * 8);
    unp8(p, h);
#pragma unroll
    for (int j = 0; j < 8; j++)
      h[j] = fmaxf(fmaf(h[j], ss[c8 * 8 + j], ss[128 + c8 * 8 + j]), 0.f);  // relu: src layers 0..3 all relu'd
  }
  int beg = ptr_row[n], end = ptr_row[n + 1];
  float acc[8] = {0.f, 0.f, 0.f, 0.f, 0.f, 0.f, 0.f, 0.f};
  for (int i = beg; i < end; i++) {
    int e = adj_row[i];
    int a0 = ea[e * 3 + 0], a1 = ea[e * 3 + 1], a2 = ea[e * 3 + 2];
    const float* p0 = be + (size_t)a0 * HD + c8 * 8;
    const float* p1 = be + (size_t)(BVOC + a1) * HD + c8 * 8;
    const float* p2 = be + (size_t)(2 * BVOC + a2) * HD + c8 * 8;
    float4 x0 = *(const float4*)p0, x1 = *(const float4*)(p0 + 4);
    float4 y0 = *(const float4*)p1, y1 = *(const float4*)(p1 + 4);
    float4 z0 = *(const float4*)p2, z1 = *(const float4*)(p2 + 4);
    acc[0] += x0.x + y0.x + z0.x; acc[1] += x0.y + y0.y + z0.y;
    acc[2] += x0.z + y0.z + z0.z; acc[3] += x0.w + y0.w + z0.w;
    acc[4] += x1.x + y1.x + z1.x; acc[5] += x1.y + y1.y + z1.y;
    acc[6] += x1.z + y1.z + z1.z; acc[7] += x1.w + y1.w + z1.w;
  }
  float iv = inv[n];
#pragma unroll
  for (int j = 0; j < 8; j++) h[j] = fmaf(acc[j], iv, h[j]);
  *(uint4*)(A + (size_t)n * HD + c8 * 8) = pk8(h);
}

// ---------------- GEMM1 with fused GIN aggregation ----------------
// z = (1+eps)*A[n] + sum_{in(col)} A[src]  built in fp32 registers (no z tensor),
// split hi/lo, 3-MFMA vs split W1.  Out: Z1 bf16 + BN stats.
__global__ __launch_bounds__(512, 4) void gemm1_aggr_k(
    const u16* __restrict__ A, const int* __restrict__ ptr_col,
    const int* __restrict__ adj_col, const float* __restrict__ eps, int lyr,
    const u16* __restrict__ Whi, const u16* __restrict__ Wlo,
    const float* __restrict__ bias, u16* __restrict__ Z1,
    float* __restrict__ stats) {
  __shared__ u16 sW[2 * HD * HD];     // 64 KB: hi then lo, [col][k], XOR-swizzled
  const int tid = threadIdx.x;
#pragma unroll
  for (int p = 0; p < 4; p++) {
    int idx = tid + p * 512;
    int col = idx >> 4, k16 = idx & 15;
    uint4 vh = *(const uint4*)(Whi + idx * 8);
    uint4 vl = *(const uint4*)(Wlo + idx * 8);
    int so = (col << 7) + ((k16 << 3) ^ ((col & 7) << 3));
    *(uint4*)(sW + so) = vh;
    *(uint4*)(sW + HD * HD + so) = vl;
  }
  __syncthreads();

  const float se = 1.0f + eps[lyr];
  const int l = tid & 63, w = tid >> 6;
  const int lr = l & 15, lk = l >> 4;
  const int rw = blockIdx.x * GBM + w * 32;
  int beg[2], end[2];
#pragma unroll
  for (int i = 0; i < 2; i++) {
    int gr = rw + i * 16 + lr;
    beg[i] = (gr < NN) ? ptr_col[gr] : 0;
    end[i] = (gr < NN) ? ptr_col[gr + 1] : 0;
  }
  f32x4 acc[2][8];
#pragma unroll
  for (int i = 0; i < 2; i++)
#pragma unroll
    for (int j = 0; j < 8; j++) acc[i][j] = (f32x4){0.f, 0.f, 0.f, 0.f};

#pragma unroll
  for (int ks = 0; ks < 4; ks++) {
    const int kb = ks * 32 + lk * 8;
    bf16x8 ah[2], al[2];
#pragma unroll
    for (int i = 0; i < 2; i++) {
      int gr = rw + i * 16 + lr;
      float v[8] = {0.f, 0.f, 0.f, 0.f, 0.f, 0.f, 0.f, 0.f};
      if (gr < NN) {
        uint4 p = *(const uint4*)(A + (size_t)gr * HD + kb);
        unp8(p, v);
#pragma unroll
        for (int j = 0; j < 8; j++) v[j] *= se;
        for (int e = beg[i]; e < end[i]; e++) {
          int src = adj_col[e];
          uint4 q = *(const uint4*)(A + (size_t)src * HD + kb);
          float u[8]; unp8(q, u);
#pragma unroll
          for (int j = 0; j < 8; j++) v[j] += u[j];
        }
      }
      split8(v, ah[i], al[i]);
    }
#pragma unroll
    for (int jt = 0; jt < 8; jt++) {
      int col = jt * 16 + lr;
      int so = (col << 7) + (kb ^ ((col & 7) << 3));
      bf16x8 bh = *(const bf16x8*)(sW + so);
      bf16x8 bl = *(const bf16x8*)(sW + HD * HD + so);
#pragma unroll
      for (int i = 0; i < 2; i++) {
        acc[i][jt] = __builtin_amdgcn_mfma_f32_16x16x32_bf16(ah[i], bh, acc[i][jt], 0, 0, 0);
        acc[i][jt] = __builtin_amdgcn_mfma_f32_16x16x32_bf16(al[i], bh, acc[i][jt], 0, 0, 0);
        acc[i][jt] = __builtin_amdgcn_mfma_f32_16x16x32_bf16(ah[i], bl, acc[i][jt], 0, 0, 0);
      }
    }
  }

  // epilogue: +bias, BN stats (fp32 pre-rounding), packed bf16 stores
  float bb[8];
#pragma unroll
  for (int jt = 0; jt < 8; jt++) bb[jt] = bias[jt * 16 + lr];
  float cs[8], cq[8];
#pragma unroll
  for (int jt = 0; jt < 8; jt++) { cs[jt] = 0.f; cq[jt] = 0.f; }
#pragma unroll
  for (int i = 0; i < 2; i++)
#pragma unroll
    for (int j = 0; j < 4; j++) {
      int gr = rw + i * 16 + lk * 4 + j;
      bool ok = gr < NN;
#pragma unroll
      for (int jt = 0; jt < 8; jt++) {
        float o = acc[i][jt][j] + bb[jt];
        if (ok) { cs[jt] += o; cq[jt] += o * o; }
        float on = __shfl_xor(o, 1);
        u32 pw = cvtpk(o, on);
        if (ok && !(l & 1))
          *(u32*)(Z1 + (size_t)gr * HD + jt * 16 + lr) = pw;
      }
    }
#pragma unroll
  for (int jt = 0; jt < 8; jt++) {
    cs[jt] += __shfl_xor(cs[jt], 16); cs[jt] += __shfl_xor(cs[jt], 32);
    cq[jt] += __shfl_xor(cq[jt], 16); cq[jt] += __shfl_xor(cq[jt], 32);
  }
  __syncthreads();
  float* sS = (float*)sW;
  if (lk == 0) {
#pragma unroll
    for (int jt = 0; jt < 8; jt++) {
      sS[w * HD + jt * 16 + lr] = cs[jt];
      sS[1024 + w * HD + jt * 16 + lr] = cq[jt];
    }
  }
  __syncthreads();
  if (tid < HD) {
    float s = 0.f, q = 0.f;
#pragma unroll
    for (int g = 0; g < 8; g++) { s += sS[g * HD + tid]; q += sS[1024 + g * HD + tid]; }
    atomAddF(&stats[tid], s);
    atomAddF(&stats[HD + tid], q);
  }
}

// ---------------- GEMM2: relu(BN1(Z1)) @ W2 + b2 -> Z2 bf16 + BN stats ----------------
__global__ __launch_bounds__(512, 4) void gemm2_k(
    const u16* __restrict__ Z1, const float* __restrict__ ss,
    const u16* __restrict__ Whi, const u16* __restrict__ Wlo,
    const float* __restrict__ bias, u16* __restrict__ Z2,
    float* __restrict__ stats) {
  __shared__ u16 sW[2 * HD * HD];
  const int tid = threadIdx.x;
#pragma unroll
  for (int p = 0; p < 4; p++) {
    int idx = tid + p * 512;
    int col = idx >> 4, k16 = idx & 15;
    uint4 vh = *(const uint4*)(Whi + idx * 8);
    uint4 vl = *(const uint4*)(Wlo + idx * 8);
    int so = (col << 7) + ((k16 << 3) ^ ((col & 7) << 3));
    *(uint4*)(sW + so) = vh;
    *(uint4*)(sW + HD * HD + so) = vl;
  }
  __syncthreads();

  const int l = tid & 63, w = tid >> 6;
  const int lr = l & 15, lk = l >> 4;
  const int rw = blockIdx.x * GBM + w * 32;
  f32x4 acc[2][8];
#pragma unroll
  for (int i = 0; i < 2; i++)
#pragma unroll
    for (int j = 0; j < 8; j++) acc[i][j] = (f32x4){0.f, 0.f, 0.f, 0.f};

#pragma unroll
  for (int ks = 0; ks < 4; ks++) {
    const int kb = ks * 32 + lk * 8;
    bf16x8 ah[2], al[2];
#pragma unroll
    for (int i = 0; i < 2; i++) {
      int gr = rw + i * 16 + lr;
      uint4 p = make_uint4(0u, 0u, 0u, 0u);
      if (gr < NN) p = *(const uint4*)(Z1 + (size_t)gr * HD + kb);
      float v[8]; unp8(p, v);
#pragma unroll
      for (int j = 0; j < 8; j++)
        v[j] = fmaxf(fmaf(v[j], ss[kb + j], ss[HD + kb + j]), 0.f);
      split8(v, ah[i], al[i]);
    }
#pragma unroll
    for (int jt = 0; jt < 8; jt++) {
      int col = jt * 16 + lr;
      int so = (col << 7) + (kb ^ ((col & 7) << 3));
      bf16x8 bh = *(const bf16x8*)(sW + so);
      bf16x8 bl = *(const bf16x8*)(sW + HD * HD + so);
#pragma unroll
      for (int i = 0; i < 2; i++) {
        acc[i][jt] = __builtin_amdgcn_mfma_f32_16x16x32_bf16(ah[i], bh, acc[i][jt], 0, 0, 0);
        acc[i][jt] = __builtin_amdgcn_mfma_f32_16x16x32_bf16(al[i], bh, acc[i][jt], 0, 0, 0);
        acc[i][jt] = __builtin_amdgcn_mfma_f32_16x16x32_bf16(ah[i], bl, acc[i][jt], 0, 0, 0);
      }
    }
  }

  float bb[8];
#pragma unroll
  for (int jt = 0; jt < 8; jt++) bb[jt] = bias[jt * 16 + lr];
  float cs[8], cq[8];
#pragma unroll
  for (int jt = 0; jt < 8; jt++) { cs[jt] = 0.f; cq[jt] = 0.f; }
#pragma unroll
  for (int i = 0; i < 2; i++)
#pragma unroll
    for (int j = 0; j < 4; j++) {
      int gr = rw + i * 16 + lk * 4 + j;
      bool ok = gr < NN;
#pragma unroll
      for (int jt = 0; jt < 8; jt++) {
        float o = acc[i][jt][j] + bb[jt];
        if (ok) { cs[jt] += o; cq[jt] += o * o; }
        float on = __shfl_xor(o, 1);
        u32 pw = cvtpk(o, on);
        if (ok && !(l & 1))
          *(u32*)(Z2 + (size_t)gr * HD + jt * 16 + lr) = pw;
      }
    }
#pragma unroll
  for (int jt = 0; jt < 8; jt++) {
    cs[jt] += __shfl_xor(cs[jt], 16); cs[jt] += __shfl_xor(cs[jt], 32);
    cq[jt] += __shfl_xor(cq[jt], 16); cq[jt] += __shfl_xor(cq[jt], 32);
  }
  __syncthreads();
  float* sS = (float*)sW;
  if (lk == 0) {
#pragma unroll
    for (int jt = 0; jt < 8; jt++) {
      sS[w * HD + jt * 16 + lr] = cs[jt];
      sS[1024 + w * HD + jt * 16 + lr] = cq[jt];
    }
  }
  __syncthreads();
  if (tid < HD) {
    float s = 0.f, q = 0.f;
#pragma unroll
    for (int g = 0; g < 8; g++) { s += sS[g * HD + tid]; q += sS[1024 + g * HD + tid]; }
    atomAddF(&stats[tid], s);
    atomAddF(&stats[HD + tid], q);
  }
}

__global__ __launch_bounds__(128) void scale_shift_k(float* __restrict__ stats,
    const float* __restrict__ g, const float* __restrict__ b) {
  int c = threadIdx.x;
  float mean = stats[c] * (1.0f / NN);
  float var = stats[HD + c] * (1.0f / NN) - mean * mean;
  float sc = g[c] * rsqrtf(var + BN_EPS);
  stats[256 + c] = sc;
  stats[384 + c] = fmaf(-mean, sc, b[c]);
}

// fused BN (no relu, layer 4) + global_add_pool + 2-layer MLP head; one block per graph
__global__ __launch_bounds__(128) void pool_final_k(const u16* __restrict__ Z2,
    const float* __restrict__ ss, const int* __restrict__ gp,
    const float* __restrict__ cw1, const float* __restrict__ cb1,
    const float* __restrict__ cw2, const float* __restrict__ cb2,
    float* __restrict__ out) {
  __shared__ float sp[128];
  __shared__ float sh[128];
  int g = blockIdx.x, t = threadIdx.x;
  int beg = gp[g], end = gp[g + 1];
  float acc = 0.f;
  for (int n = beg; n < end; n++) acc += bf2f(Z2[(size_t)n * HD + t]);
  // sum of BN(v) = sc * sum(v) + count * shift
  sp[t] = fmaf(acc, ss[t], (float)(end - beg) * ss[128 + t]);
  __syncthreads();
  float h1 = cb1[t];
#pragma unroll
  for (int k = 0; k < HD; k++) h1 = fmaf(sp[k], cw1[k * HD + t], h1);
  h1 = fmaxf(h1, 0.f);
  sh[t] = h1 * cw2[t];
  __syncthreads();
  for (int s = 64; s >= 1; s >>= 1) {
    if (t < s) sh[t] += sh[t + s];
    __syncthreads();
  }
  if (t == 0) out[g] = sh[0] + cb2[0];
}

extern "C" void kernel_launch(void* const* d_in, const int* in_sizes, int n_in,
                              void* d_out, int out_size, void* d_ws, size_t ws_size,
                              hipStream_t stream) {
  const int*   x        = (const int*)d_in[0];
  const int*   ei       = (const int*)d_in[1];
  const int*   ea       = (const int*)d_in[2];
  const int*   batch    = (const int*)d_in[3];
  const float* atom_emb = (const float*)d_in[4];
  const float* bond_emb = (const float*)d_in[5];
  const float* eps      = (const float*)d_in[6];
  const float* w1       = (const float*)d_in[7];
  const float* b1       = (const float*)d_in[8];
  const float* bn1_g    = (const float*)d_in[9];
  const float* bn1_b    = (const float*)d_in[10];
  const float* w2       = (const float*)d_in[11];
  const float* b2       = (const float*)d_in[12];
  const float* bn_g     = (const float*)d_in[13];
  const float* bn_b     = (const float*)d_in[14];
  const float* cw1      = (const float*)d_in[15];
  const float* cb1      = (const float*)d_in[16];
  const float* cw2      = (const float*)d_in[17];
  const float* cb2      = (const float*)d_in[18];
  float* out = (float*)d_out;

  const size_t NH = (size_t)NN * HD;
  float* ws = (float*)d_ws;
  float* stats   = ws;                               // 5*1024 floats
  int*   ptr_row = (int*)(ws + 5 * 1024);            // NN+1
  int*   ptr_col = ptr_row + (NN + 1);               // NN+1
  int*   adj_row = ptr_col + (NN + 1);               // NE
  int*   adj_col = adj_row + NE;                     // NE
  int*   gp      = adj_col + NE;                     // NG+1
  float* inv     = (float*)(gp + (NG + 1));          // NN
  size_t off = 5 * 1024 + 2 * (size_t)(NN + 1) + 2 * (size_t)NE + (NG + 1) + NN;
  off = (off + 3) & ~(size_t)3;                      // 16B align
  float* B = ws + off;                               // NH fp32 bytes, holds Z1 | Z2 (bf16 halves)
  u16*   Z1 = (u16*)B;                               // lower NH*2 bytes
  u16*   Z2 = Z1 + NH;                               // upper NH*2 bytes
  u16*   A  = (u16*)(B + NH);                        // NH bf16 (h_in)
  u16*   Wt_hi = A + NH;                             // 10 * 128*128 bf16
  u16*   Wt_lo = Wt_hi + 10 * HD * HD;               // 10 * 128*128 bf16
  // setup-only temps aliased into B (first written by gemm1_aggr in layer 0)
  int* fillr = (int*)B;
  int* fillc = fillr + NN;
  int* bsums = fillc + NN;                           // SCAN_NB ints

  const int nb_node = (NN + 15) / 16;                        // 18750
  const int nb_e    = (NE + 255) / 256;                      // 2344

  // ---- setup: CSR build + weight split + graph offsets ----
  hipMemsetAsync(stats, 0, 5 * 1024 * sizeof(float), stream);
  hipMemsetAsync(ptr_row, 0, 2 * (NN + 1) * sizeof(int), stream);
  hipMemsetAsync(fillr, 0, 2 * NN * sizeof(int), stream);

  count_k<<<nb_e, 256, 0, stream>>>(ei, ptr_row, ptr_col);
  scan_block_k<<<SCAN_NB, 256, 0, stream>>>(ptr_row, bsums);
  scan_tops_k<<<1, 256, 0, stream>>>(bsums, &ptr_row[NN]);
  scan_add_k<<<SCAN_NB, 256, 0, stream>>>(ptr_row, bsums);
  scan_block_k<<<SCAN_NB, 256, 0, stream>>>(ptr_col, bsums);
  scan_tops_k<<<1, 256, 0, stream>>>(bsums, &ptr_col[NN]);
  scan_add_k<<<SCAN_NB, 256, 0, stream>>>(ptr_col, bsums);
  inv_k<<<(NN + 255) / 256, 256, 0, stream>>>(ptr_row, inv);
  fill_k<<<nb_e, 256, 0, stream>>>(ei, ptr_row, ptr_col, fillr, fillc, adj_row, adj_col);
  wsplit_k<<<2 * NL, 256, 0, stream>>>(w1, w2, Wt_hi, Wt_lo);
  gp_k<<<(NG + 1 + 255) / 256, 256, 0, stream>>>(batch, gp);

  // ---- layers ----
  for (int l = 0; l < NL; l++) {
    const float* be = bond_emb + (size_t)l * NBF * BVOC * HD;
    float* st = stats + (size_t)l * 1024;
    if (l == 0) {
      bond_k<true><<<nb_node, 256, 0, stream>>>(ea, be, ptr_row, adj_row, inv,
          x, atom_emb, nullptr, nullptr, A);
    } else {
      bond_k<false><<<nb_node, 256, 0, stream>>>(ea, be, ptr_row, adj_row, inv,
          nullptr, nullptr, Z2, stats + (size_t)(l - 1) * 1024 + 768, A);
    }
    gemm1_aggr_k<<<GBLK, 512, 0, stream>>>(A, ptr_col, adj_col, eps, l,
        Wt_hi + (size_t)l * HD * HD, Wt_lo + (size_t)l * HD * HD,
        b1 + (size_t)l * HD, Z1, st);
    scale_shift_k<<<1, 128, 0, stream>>>(st, bn1_g + (size_t)l * HD, bn1_b + (size_t)l * HD);
    gemm2_k<<<GBLK, 512, 0, stream>>>(Z1, st + 256,
        Wt_hi + (size_t)(NL + l) * HD * HD, Wt_lo + (size_t)(NL + l) * HD * HD,
        b2 + (size_t)l * HD, Z2, st + 512);
    scale_shift_k<<<1, 128, 0, stream>>>(st + 512, bn_g + (size_t)l * HD, bn_b + (size_t)l * HD);
  }

  // ---- pooled head (BN of layer 4 fused, no relu) ----
  pool_final_k<<<NG, 128, 0, stream>>>(Z2, stats + 4 * 1024 + 768, gp,
      cw1, cb1, cw2, cb2, out);
}

// Round 4
// 1562.335 us; speedup vs baseline: 1.9125x; 1.1845x over previous
//
#include <hip/hip_runtime.h>
#include <cstdint>

#define NN 300000
#define NE 600000
#define HD 128
#define NL 5
#define NG 8192
#define AVOC 128
#define BVOC 8
#define NAF 9
#define NBF 3
#define BN_EPS 1e-5f

#define SCAN_B 2048
#define SCAN_NB ((NN + SCAN_B - 1) / SCAN_B)   // 147

#define G1ROWS 128
#define G1BLK ((NN + G1ROWS - 1) / G1ROWS)     // 2344
#define GBM 256
#define GBLK ((NN + GBM - 1) / GBM)            // 1172

typedef unsigned short u16;
typedef unsigned int u32;
typedef __attribute__((ext_vector_type(8))) short bf16x8;
typedef __attribute__((ext_vector_type(4))) float f32x4;

static __device__ __forceinline__ void atomAddF(float* p, float v) { unsafeAtomicAdd(p, v); }

static __device__ __forceinline__ float bf2f(u16 v) {
  union { u32 u; float f; } c; c.u = ((u32)v) << 16; return c.f;
}
static __device__ __forceinline__ u16 f2bf(float f) {
  union { float f; u32 u; } c; c.f = f;
  u32 u = c.u;
  return (u16)((u + 0x7FFFu + ((u >> 16) & 1u)) >> 16);  // RNE
}
static __device__ __forceinline__ u32 cvtpk(float a, float b) {
  u32 r;
  asm("v_cvt_pk_bf16_f32 %0, %1, %2" : "=v"(r) : "v"(a), "v"(b));
  return r;  // lo16 = bf16(a), hi16 = bf16(b), RNE
}
static __device__ __forceinline__ void unp8(uint4 p, float* v) {
  v[0] = bf2f((u16)(p.x & 0xffff)); v[1] = bf2f((u16)(p.x >> 16));
  v[2] = bf2f((u16)(p.y & 0xffff)); v[3] = bf2f((u16)(p.y >> 16));
  v[4] = bf2f((u16)(p.z & 0xffff)); v[5] = bf2f((u16)(p.z >> 16));
  v[6] = bf2f((u16)(p.w & 0xffff)); v[7] = bf2f((u16)(p.w >> 16));
}
static __device__ __forceinline__ uint4 pk8(const float* v) {
  uint4 p;
  p.x = ((u32)f2bf(v[1]) << 16) | f2bf(v[0]);
  p.y = ((u32)f2bf(v[3]) << 16) | f2bf(v[2]);
  p.z = ((u32)f2bf(v[5]) << 16) | f2bf(v[4]);
  p.w = ((u32)f2bf(v[7]) << 16) | f2bf(v[6]);
  return p;
}

// split fp32[8] -> hi bf16x8 + lo bf16x8  (hi+lo represents v to ~2^-17 rel)
static __device__ __forceinline__ void split8(const float* v, bf16x8& hi, bf16x8& lo) {
  union { u32 u[4]; bf16x8 h; } H, L;
  H.u[0] = cvtpk(v[0], v[1]); H.u[1] = cvtpk(v[2], v[3]);
  H.u[2] = cvtpk(v[4], v[5]); H.u[3] = cvtpk(v[6], v[7]);
  float r[8];
  r[0] = bf2f((u16)(H.u[0] & 0xffff)); r[1] = bf2f((u16)(H.u[0] >> 16));
  r[2] = bf2f((u16)(H.u[1] & 0xffff)); r[3] = bf2f((u16)(H.u[1] >> 16));
  r[4] = bf2f((u16)(H.u[2] & 0xffff)); r[5] = bf2f((u16)(H.u[2] >> 16));
  r[6] = bf2f((u16)(H.u[3] & 0xffff)); r[7] = bf2f((u16)(H.u[3] >> 16));
  L.u[0] = cvtpk(v[0] - r[0], v[1] - r[1]); L.u[1] = cvtpk(v[2] - r[2], v[3] - r[3]);
  L.u[2] = cvtpk(v[4] - r[4], v[5] - r[5]); L.u[3] = cvtpk(v[6] - r[6], v[7] - r[7]);
  hi = H.h; lo = L.h;
}

// ================= CSR construction =================
__global__ __launch_bounds__(256) void count_k(const int* __restrict__ ei,
    int* __restrict__ cnt_row, int* __restrict__ cnt_col) {
  int e = blockIdx.x * 256 + threadIdx.x;
  if (e >= NE) return;
  atomicAdd(&cnt_row[ei[e]], 1);
  atomicAdd(&cnt_col[ei[NE + e]], 1);
}

__global__ __launch_bounds__(256) void scan_block_k(int* __restrict__ P, int* __restrict__ bsum) {
  __shared__ int s[256];
  int b = blockIdx.x, t = threadIdx.x;
  int base = b * SCAN_B + t * 8;
  int v[8]; int ts = 0;
#pragma unroll
  for (int j = 0; j < 8; j++) { v[j] = (base + j < NN) ? P[base + j] : 0; ts += v[j]; }
  s[t] = ts;
  __syncthreads();
  for (int off = 1; off < 256; off <<= 1) {
    int tmp = 0;
    if (t >= off) tmp = s[t - off];
    __syncthreads();
    if (t >= off) s[t] += tmp;
    __syncthreads();
  }
  if (t == 255) bsum[b] = s[255];
  int run = (t == 0) ? 0 : s[t - 1];
#pragma unroll
  for (int j = 0; j < 8; j++) {
    if (base + j < NN) P[base + j] = run;
    run += v[j];
  }
}

__global__ __launch_bounds__(256) void scan_tops_k(int* __restrict__ bsum, int* __restrict__ totOut) {
  __shared__ int s[256];
  int t = threadIdx.x;
  s[t] = (t < SCAN_NB) ? bsum[t] : 0;
  __syncthreads();
  for (int off = 1; off < 256; off <<= 1) {
    int tmp = 0;
    if (t >= off) tmp = s[t - off];
    __syncthreads();
    if (t >= off) s[t] += tmp;
    __syncthreads();
  }
  if (t < SCAN_NB) bsum[t] = (t == 0) ? 0 : s[t - 1];
  if (t == 255) *totOut = s[255];
}

__global__ __launch_bounds__(256) void scan_add_k(int* __restrict__ P, const int* __restrict__ bsum) {
  int b = blockIdx.x, t = threadIdx.x;
  int off = bsum[b];
  int base = b * SCAN_B + t * 8;
#pragma unroll
  for (int j = 0; j < 8; j++)
    if (base + j < NN) P[base + j] += off;
}

__global__ __launch_bounds__(256) void fill_k(const int* __restrict__ ei,
    const int* __restrict__ ptr_row, const int* __restrict__ ptr_col,
    int* __restrict__ fillr, int* __restrict__ fillc,
    int* __restrict__ adj_row, int* __restrict__ adj_col) {
  int e = blockIdx.x * 256 + threadIdx.x;
  if (e >= NE) return;
  int r = ei[e], c = ei[NE + e];
  int p1 = atomicAdd(&fillr[r], 1);
  adj_row[ptr_row[r] + p1] = e;
  int p2 = atomicAdd(&fillc[c], 1);
  adj_col[ptr_col[c] + p2] = r;
}

__global__ __launch_bounds__(256) void inv_k(const int* __restrict__ ptr_row, float* __restrict__ inv) {
  int n = blockIdx.x * 256 + threadIdx.x;
  if (n < NN) inv[n] = 1.0f / ((float)(ptr_row[n + 1] - ptr_row[n]) + 1.0f);
}

__global__ __launch_bounds__(256) void gp_k(const int* __restrict__ batch, int* __restrict__ gp) {
  int g = blockIdx.x * 256 + threadIdx.x;
  if (g > NG) return;
  int lo = 0, hi = NN;
  while (lo < hi) { int mid = (lo + hi) >> 1; if (batch[mid] < g) lo = mid + 1; else hi = mid; }
  gp[g] = lo;
}

// W split/transpose: Wt[m][c][k] = bf16_hi/lo of W_m[k][c];  m<5 -> w1[m], else w2[m-5]
__global__ __launch_bounds__(256) void wsplit_k(const float* __restrict__ w1,
    const float* __restrict__ w2, u16* __restrict__ Wt_hi, u16* __restrict__ Wt_lo) {
  int m = blockIdx.x;
  const float* W = (m < NL) ? (w1 + (size_t)m * HD * HD) : (w2 + (size_t)(m - NL) * HD * HD);
  int t = threadIdx.x;
  for (int p = 0; p < 64; p++) {
    int o = p * 256 + t;            // linear over [c][k]
    int c = o >> 7, k = o & 127;
    float w = W[k * HD + c];
    u16 hi = f2bf(w);
    float lo = w - bf2f(hi);
    Wt_hi[(size_t)m * HD * HD + o] = hi;
    Wt_lo[(size_t)m * HD * HD + o] = f2bf(lo);
  }
}

// ================= model kernels =================

// bond + h_in, fused with either the atom encoder (ENC, layer 0) or the
// previous layer's BN+relu (from Z2 bf16 + ss).  h_in -> A (bf16).
template<bool ENC>
__global__ __launch_bounds__(256) void bond_k(const int* __restrict__ ea,
    const float* __restrict__ be, const int* __restrict__ ptr_row,
    const int* __restrict__ adj_row, const float* __restrict__ inv,
    const int* __restrict__ x, const float* __restrict__ emb,
    const u16* __restrict__ Z2, const float* __restrict__ ss,
    u16* __restrict__ A) {
  __shared__ int sx[16 * NAF];
  int t = threadIdx.x;
  int nb = blockIdx.x * 16;
  int n = nb + (t >> 4);
  int c8 = t & 15;
  if constexpr (ENC) {
    if (t < 16 * NAF && nb * NAF + t < NN * NAF) sx[t] = x[nb * NAF + t];
    __syncthreads();
  }
  if (n >= NN) return;
  float h[8];
  if constexpr (ENC) {
#pragma unroll
    for (int j = 0; j < 8; j++) h[j] = 0.f;
#pragma unroll
    for (int f = 0; f < NAF; f++) {
      int v = sx[(t >> 4) * NAF + f];
      const float* e = emb + ((size_t)(f * AVOC + v)) * HD + c8 * 8;
      float4 e0 = *(const float4*)e;
      float4 e1 = *(const float4*)(e + 4);
      h[0] += e0.x; h[1] += e0.y; h[2] += e0.z; h[3] += e0.w;
      h[4] += e1.x; h[5] += e1.y; h[6] += e1.z; h[7] += e1.w;
    }
  } else {
    uint4 p = *(const uint4*)(Z2 + (size_t)n * HD + c8 * 8);
    unp8(p, h);
#pragma unroll
    for (int j = 0; j < 8; j++)
      h[j] = fmaxf(fmaf(h[j], ss[c8 * 8 + j], ss[128 + c8 * 8 + j]), 0.f);
  }
  int beg = ptr_row[n], end = ptr_row[n + 1];
  float acc[8] = {0.f, 0.f, 0.f, 0.f, 0.f, 0.f, 0.f, 0.f};
  for (int i = beg; i < end; i++) {
    int e = adj_row[i];
    int a0 = ea[e * 3 + 0], a1 = ea[e * 3 + 1], a2 = ea[e * 3 + 2];
    const float* p0 = be + (size_t)a0 * HD + c8 * 8;
    const float* p1 = be + (size_t)(BVOC + a1) * HD + c8 * 8;
    const float* p2 = be + (size_t)(2 * BVOC + a2) * HD + c8 * 8;
    float4 x0 = *(const float4*)p0, x1 = *(const float4*)(p0 + 4);
    float4 y0 = *(const float4*)p1, y1 = *(const float4*)(p1 + 4);
    float4 z0 = *(const float4*)p2, z1 = *(const float4*)(p2 + 4);
    acc[0] += x0.x + y0.x + z0.x; acc[1] += x0.y + y0.y + z0.y;
    acc[2] += x0.z + y0.z + z0.z; acc[3] += x0.w + y0.w + z0.w;
    acc[4] += x1.x + y1.x + z1.x; acc[5] += x1.y + y1.y + z1.y;
    acc[6] += x1.z + y1.z + z1.z; acc[7] += x1.w + y1.w + z1.w;
  }
  float iv = inv[n];
#pragma unroll
  for (int j = 0; j < 8; j++) h[j] = fmaf(acc[j], iv, h[j]);
  *(uint4*)(A + (size_t)n * HD + c8 * 8) = pk8(h);
}

// ---------------- GEMM1 with fused GIN aggregation (gather hoisted) ----------------
// Each wave owns 16 rows; lane (lr,lk) accumulates z[cols lk*8+{0..7} of each 32-chunk]
// for row rw+lr in ONE edge walk (4 back-to-back 16B loads per edge), then
// split hi/lo and 3-MFMA vs split W1.  Out: Z1 bf16 + BN stats.
__global__ __launch_bounds__(512, 4) void gemm1_aggr_k(
    const u16* __restrict__ A, const int* __restrict__ ptr_col,
    const int* __restrict__ adj_col, const float* __restrict__ eps, int lyr,
    const u16* __restrict__ Whi, const u16* __restrict__ Wlo,
    const float* __restrict__ bias, u16* __restrict__ Z1,
    float* __restrict__ stats) {
  __shared__ u16 sW[2 * HD * HD];     // 64 KB: hi then lo, [col][k], XOR-swizzled
  const int tid = threadIdx.x;
#pragma unroll
  for (int p = 0; p < 4; p++) {
    int idx = tid + p * 512;
    int col = idx >> 4, k16 = idx & 15;
    uint4 vh = *(const uint4*)(Whi + idx * 8);
    uint4 vl = *(const uint4*)(Wlo + idx * 8);
    int so = (col << 7) + ((k16 << 3) ^ ((col & 7) << 3));
    *(uint4*)(sW + so) = vh;
    *(uint4*)(sW + HD * HD + so) = vl;
  }
  __syncthreads();

  const float se = 1.0f + eps[lyr];
  const int l = tid & 63, w = tid >> 6;
  const int lr = l & 15, lk = l >> 4;
  const int rw = blockIdx.x * G1ROWS + w * 16;  // wave's 16 rows
  const int gr = rw + lr;                       // this lane's row
  const int kb0 = lk * 8;                       // lane's col base within each 32-chunk

  float z[4][8];
#pragma unroll
  for (int ks = 0; ks < 4; ks++)
#pragma unroll
    for (int j = 0; j < 8; j++) z[ks][j] = 0.f;

  if (gr < NN) {
    const u16* ap = A + (size_t)gr * HD + kb0;
    uint4 s0 = *(const uint4*)(ap);
    uint4 s1 = *(const uint4*)(ap + 32);
    uint4 s2 = *(const uint4*)(ap + 64);
    uint4 s3 = *(const uint4*)(ap + 96);
    int beg = ptr_col[gr], end = ptr_col[gr + 1];
    {
      float v[8];
      unp8(s0, v);
#pragma unroll
      for (int j = 0; j < 8; j++) z[0][j] = v[j] * se;
      unp8(s1, v);
#pragma unroll
      for (int j = 0; j < 8; j++) z[1][j] = v[j] * se;
      unp8(s2, v);
#pragma unroll
      for (int j = 0; j < 8; j++) z[2][j] = v[j] * se;
      unp8(s3, v);
#pragma unroll
      for (int j = 0; j < 8; j++) z[3][j] = v[j] * se;
    }
    if (beg < end) {
      int src = adj_col[beg];
      for (int e = beg; e < end; e++) {
        const u16* sp = A + (size_t)src * HD + kb0;
        uint4 q0 = *(const uint4*)(sp);
        uint4 q1 = *(const uint4*)(sp + 32);
        uint4 q2 = *(const uint4*)(sp + 64);
        uint4 q3 = *(const uint4*)(sp + 96);
        if (e + 1 < end) src = adj_col[e + 1];  // break index->data chain
        float u[8];
        unp8(q0, u);
#pragma unroll
        for (int j = 0; j < 8; j++) z[0][j] += u[j];
        unp8(q1, u);
#pragma unroll
        for (int j = 0; j < 8; j++) z[1][j] += u[j];
        unp8(q2, u);
#pragma unroll
        for (int j = 0; j < 8; j++) z[2][j] += u[j];
        unp8(q3, u);
#pragma unroll
        for (int j = 0; j < 8; j++) z[3][j] += u[j];
      }
    }
  }

  bf16x8 ah[4], al[4];
#pragma unroll
  for (int ks = 0; ks < 4; ks++) split8(z[ks], ah[ks], al[ks]);

  f32x4 acc[8];
#pragma unroll
  for (int jt = 0; jt < 8; jt++) acc[jt] = (f32x4){0.f, 0.f, 0.f, 0.f};
#pragma unroll
  for (int ks = 0; ks < 4; ks++) {
    const int kb = ks * 32 + kb0;
#pragma unroll
    for (int jt = 0; jt < 8; jt++) {
      int col = jt * 16 + lr;
      int so = (col << 7) + (kb ^ ((col & 7) << 3));
      bf16x8 bh = *(const bf16x8*)(sW + so);
      bf16x8 bl = *(const bf16x8*)(sW + HD * HD + so);
      acc[jt] = __builtin_amdgcn_mfma_f32_16x16x32_bf16(ah[ks], bh, acc[jt], 0, 0, 0);
      acc[jt] = __builtin_amdgcn_mfma_f32_16x16x32_bf16(al[ks], bh, acc[jt], 0, 0, 0);
      acc[jt] = __builtin_amdgcn_mfma_f32_16x16x32_bf16(ah[ks], bl, acc[jt], 0, 0, 0);
    }
  }

  // epilogue: +bias, BN stats (fp32 pre-rounding), packed bf16 stores
  // D layout: col = jt*16 + (l&15), row = rw + (l>>4)*4 + reg
  float bb[8];
#pragma unroll
  for (int jt = 0; jt < 8; jt++) bb[jt] = bias[jt * 16 + lr];
  float cs[8], cq[8];
#pragma unroll
  for (int jt = 0; jt < 8; jt++) { cs[jt] = 0.f; cq[jt] = 0.f; }
#pragma unroll
  for (int j = 0; j < 4; j++) {
    int gr2 = rw + lk * 4 + j;
    bool ok = gr2 < NN;
#pragma unroll
    for (int jt = 0; jt < 8; jt++) {
      float o = acc[jt][j] + bb[jt];
      if (ok) { cs[jt] += o; cq[jt] += o * o; }
      float on = __shfl_xor(o, 1);
      u32 pw = cvtpk(o, on);
      if (ok && !(l & 1))
        *(u32*)(Z1 + (size_t)gr2 * HD + jt * 16 + lr) = pw;
    }
  }
#pragma unroll
  for (int jt = 0; jt < 8; jt++) {
    cs[jt] += __shfl_xor(cs[jt], 16); cs[jt] += __shfl_xor(cs[jt], 32);
    cq[jt] += __shfl_xor(cq[jt], 16); cq[jt] += __shfl_xor(cq[jt], 32);
  }
  __syncthreads();
  float* sS = (float*)sW;
  if (lk == 0) {
#pragma unroll
    for (int jt = 0; jt < 8; jt++) {
      sS[w * HD + jt * 16 + lr] = cs[jt];
      sS[1024 + w * HD + jt * 16 + lr] = cq[jt];
    }
  }
  __syncthreads();
  if (tid < HD) {
    float s = 0.f, q = 0.f;
#pragma unroll
    for (int g = 0; g < 8; g++) { s += sS[g * HD + tid]; q += sS[1024 + g * HD + tid]; }
    atomAddF(&stats[tid], s);
    atomAddF(&stats[HD + tid], q);
  }
}

// ---------------- GEMM2: relu(BN1(Z1)) @ W2 + b2 -> Z2 bf16 + BN stats ----------------
__global__ __launch_bounds__(512, 4) void gemm2_k(
    const u16* __restrict__ Z1, const float* __restrict__ ss,
    const u16* __restrict__ Whi, const u16* __restrict__ Wlo,
    const float* __restrict__ bias, u16* __restrict__ Z2,
    float* __restrict__ stats) {
  __shared__ u16 sW[2 * HD * HD];
  const int tid = threadIdx.x;
#pragma unroll
  for (int p = 0; p < 4; p++) {
    int idx = tid + p * 512;
    int col = idx >> 4, k16 = idx & 15;
    uint4 vh = *(const uint4*)(Whi + idx * 8);
    uint4 vl = *(const uint4*)(Wlo + idx * 8);
    int so = (col << 7) + ((k16 << 3) ^ ((col & 7) << 3));
    *(uint4*)(sW + so) = vh;
    *(uint4*)(sW + HD * HD + so) = vl;
  }
  __syncthreads();

  const int l = tid & 63, w = tid >> 6;
  const int lr = l & 15, lk = l >> 4;
  const int rw = blockIdx.x * GBM + w * 32;
  f32x4 acc[2][8];
#pragma unroll
  for (int i = 0; i < 2; i++)
#pragma unroll
    for (int j = 0; j < 8; j++) acc[i][j] = (f32x4){0.f, 0.f, 0.f, 0.f};

#pragma unroll
  for (int ks = 0; ks < 4; ks++) {
    const int kb = ks * 32 + lk * 8;
    bf16x8 ah[2], al[2];
#pragma unroll
    for (int i = 0; i < 2; i++) {
      int gr = rw + i * 16 + lr;
      uint4 p = make_uint4(0u, 0u, 0u, 0u);
      if (gr < NN) p = *(const uint4*)(Z1 + (size_t)gr * HD + kb);
      float v[8]; unp8(p, v);
#pragma unroll
      for (int j = 0; j < 8; j++)
        v[j] = fmaxf(fmaf(v[j], ss[kb + j], ss[HD + kb + j]), 0.f);
      split8(v, ah[i], al[i]);
    }
#pragma unroll
    for (int jt = 0; jt < 8; jt++) {
      int col = jt * 16 + lr;
      int so = (col << 7) + (kb ^ ((col & 7) << 3));
      bf16x8 bh = *(const bf16x8*)(sW + so);
      bf16x8 bl = *(const bf16x8*)(sW + HD * HD + so);
#pragma unroll
      for (int i = 0; i < 2; i++) {
        acc[i][jt] = __builtin_amdgcn_mfma_f32_16x16x32_bf16(ah[i], bh, acc[i][jt], 0, 0, 0);
        acc[i][jt] = __builtin_amdgcn_mfma_f32_16x16x32_bf16(al[i], bh, acc[i][jt], 0, 0, 0);
        acc[i][jt] = __builtin_amdgcn_mfma_f32_16x16x32_bf16(ah[i], bl, acc[i][jt], 0, 0, 0);
      }
    }
  }

  float bb[8];
#pragma unroll
  for (int jt = 0; jt < 8; jt++) bb[jt] = bias[jt * 16 + lr];
  float cs[8], cq[8];
#pragma unroll
  for (int jt = 0; jt < 8; jt++) { cs[jt] = 0.f; cq[jt] = 0.f; }
#pragma unroll
  for (int i = 0; i < 2; i++)
#pragma unroll
    for (int j = 0; j < 4; j++) {
      int gr = rw + i * 16 + lk * 4 + j;
      bool ok = gr < NN;
#pragma unroll
      for (int jt = 0; jt < 8; jt++) {
        float o = acc[i][jt][j] + bb[jt];
        if (ok) { cs[jt] += o; cq[jt] += o * o; }
        float on = __shfl_xor(o, 1);
        u32 pw = cvtpk(o, on);
        if (ok && !(l & 1))
          *(u32*)(Z2 + (size_t)gr * HD + jt * 16 + lr) = pw;
      }
    }
#pragma unroll
  for (int jt = 0; jt < 8; jt++) {
    cs[jt] += __shfl_xor(cs[jt], 16); cs[jt] += __shfl_xor(cs[jt], 32);
    cq[jt] += __shfl_xor(cq[jt], 16); cq[jt] += __shfl_xor(cq[jt], 32);
  }
  __syncthreads();
  float* sS = (float*)sW;
  if (lk == 0) {
#pragma unroll
    for (int jt = 0; jt < 8; jt++) {
      sS[w * HD + jt * 16 + lr] = cs[jt];
      sS[1024 + w * HD + jt * 16 + lr] = cq[jt];
    }
  }
  __syncthreads();
  if (tid < HD) {
    float s = 0.f, q = 0.f;
#pragma unroll
    for (int g = 0; g < 8; g++) { s += sS[g * HD + tid]; q += sS[1024 + g * HD + tid]; }
    atomAddF(&stats[tid], s);
    atomAddF(&stats[HD + tid], q);
  }
}

__global__ __launch_bounds__(128) void scale_shift_k(float* __restrict__ stats,
    const float* __restrict__ g, const float* __restrict__ b) {
  int c = threadIdx.x;
  float mean = stats[c] * (1.0f / NN);
  float var = stats[HD + c] * (1.0f / NN) - mean * mean;
  float sc = g[c] * rsqrtf(var + BN_EPS);
  stats[256 + c] = sc;
  stats[384 + c] = fmaf(-mean, sc, b[c]);
}

// fused BN (no relu, layer 4) + global_add_pool + 2-layer MLP head; one block per graph
__global__ __launch_bounds__(128) void pool_final_k(const u16* __restrict__ Z2,
    const float* __restrict__ ss, const int* __restrict__ gp,
    const float* __restrict__ cw1, const float* __restrict__ cb1,
    const float* __restrict__ cw2, const float* __restrict__ cb2,
    float* __restrict__ out) {
  __shared__ float sp[128];
  __shared__ float sh[128];
  int g = blockIdx.x, t = threadIdx.x;
  int beg = gp[g], end = gp[g + 1];
  float acc = 0.f;
  for (int n = beg; n < end; n++) acc += bf2f(Z2[(size_t)n * HD + t]);
  sp[t] = fmaf(acc, ss[t], (float)(end - beg) * ss[128 + t]);
  __syncthreads();
  float h1 = cb1[t];
#pragma unroll
  for (int k = 0; k < HD; k++) h1 = fmaf(sp[k], cw1[k * HD + t], h1);
  h1 = fmaxf(h1, 0.f);
  sh[t] = h1 * cw2[t];
  __syncthreads();
  for (int s = 64; s >= 1; s >>= 1) {
    if (t < s) sh[t] += sh[t + s];
    __syncthreads();
  }
  if (t == 0) out[g] = sh[0] + cb2[0];
}

extern "C" void kernel_launch(void* const* d_in, const int* in_sizes, int n_in,
                              void* d_out, int out_size, void* d_ws, size_t ws_size,
                              hipStream_t stream) {
  const int*   x        = (const int*)d_in[0];
  const int*   ei       = (const int*)d_in[1];
  const int*   ea       = (const int*)d_in[2];
  const int*   batch    = (const int*)d_in[3];
  const float* atom_emb = (const float*)d_in[4];
  const float* bond_emb = (const float*)d_in[5];
  const float* eps      = (const float*)d_in[6];
  const float* w1       = (const float*)d_in[7];
  const float* b1       = (const float*)d_in[8];
  const float* bn1_g    = (const float*)d_in[9];
  const float* bn1_b    = (const float*)d_in[10];
  const float* w2       = (const float*)d_in[11];
  const float* b2       = (const float*)d_in[12];
  const float* bn_g     = (const float*)d_in[13];
  const float* bn_b     = (const float*)d_in[14];
  const float* cw1      = (const float*)d_in[15];
  const float* cb1      = (const float*)d_in[16];
  const float* cw2      = (const float*)d_in[17];
  const float* cb2      = (const float*)d_in[18];
  float* out = (float*)d_out;

  const size_t NH = (size_t)NN * HD;
  float* ws = (float*)d_ws;
  float* stats   = ws;                               // 5*1024 floats
  int*   ptr_row = (int*)(ws + 5 * 1024);            // NN+1
  int*   ptr_col = ptr_row + (NN + 1);               // NN+1
  int*   adj_row = ptr_col + (NN + 1);               // NE
  int*   adj_col = adj_row + NE;                     // NE
  int*   gp      = adj_col + NE;                     // NG+1
  float* inv     = (float*)(gp + (NG + 1));          // NN
  size_t off = 5 * 1024 + 2 * (size_t)(NN + 1) + 2 * (size_t)NE + (NG + 1) + NN;
  off = (off + 3) & ~(size_t)3;                      // 16B align
  float* B = ws + off;                               // NH fp32 bytes, holds Z1 | Z2 (bf16 halves)
  u16*   Z1 = (u16*)B;                               // lower NH*2 bytes
  u16*   Z2 = Z1 + NH;                               // upper NH*2 bytes
  u16*   A  = (u16*)(B + NH);                        // NH bf16 (h_in)
  u16*   Wt_hi = A + NH;                             // 10 * 128*128 bf16
  u16*   Wt_lo = Wt_hi + 10 * HD * HD;               // 10 * 128*128 bf16
  // setup-only temps aliased into B (first written by gemm1_aggr in layer 0)
  int* fillr = (int*)B;
  int* fillc = fillr + NN;
  int* bsums = fillc + NN;                           // SCAN_NB ints

  const int nb_node = (NN + 15) / 16;                        // 18750
  const int nb_e    = (NE + 255) / 256;                      // 2344

  // ---- setup: CSR build + weight split + graph offsets ----
  hipMemsetAsync(stats, 0, 5 * 1024 * sizeof(float), stream);
  hipMemsetAsync(ptr_row, 0, 2 * (NN + 1) * sizeof(int), stream);
  hipMemsetAsync(fillr, 0, 2 * NN * sizeof(int), stream);

  count_k<<<nb_e, 256, 0, stream>>>(ei, ptr_row, ptr_col);
  scan_block_k<<<SCAN_NB, 256, 0, stream>>>(ptr_row, bsums);
  scan_tops_k<<<1, 256, 0, stream>>>(bsums, &ptr_row[NN]);
  scan_add_k<<<SCAN_NB, 256, 0, stream>>>(ptr_row, bsums);
  scan_block_k<<<SCAN_NB, 256, 0, stream>>>(ptr_col, bsums);
  scan_tops_k<<<1, 256, 0, stream>>>(bsums, &ptr_col[NN]);
  scan_add_k<<<SCAN_NB, 256, 0, stream>>>(ptr_col, bsums);
  inv_k<<<(NN + 255) / 256, 256, 0, stream>>>(ptr_row, inv);
  fill_k<<<nb_e, 256, 0, stream>>>(ei, ptr_row, ptr_col, fillr, fillc, adj_row, adj_col);
  wsplit_k<<<2 * NL, 256, 0, stream>>>(w1, w2, Wt_hi, Wt_lo);
  gp_k<<<(NG + 1 + 255) / 256, 256, 0, stream>>>(batch, gp);

  // ---- layers ----
  for (int l = 0; l < NL; l++) {
    const float* be = bond_emb + (size_t)l * NBF * BVOC * HD;
    float* st = stats + (size_t)l * 1024;
    if (l == 0) {
      bond_k<true><<<nb_node, 256, 0, stream>>>(ea, be, ptr_row, adj_row, inv,
          x, atom_emb, nullptr, nullptr, A);
    } else {
      bond_k<false><<<nb_node, 256, 0, stream>>>(ea, be, ptr_row, adj_row, inv,
          nullptr, nullptr, Z2, stats + (size_t)(l - 1) * 1024 + 768, A);
    }
    gemm1_aggr_k<<<G1BLK, 512, 0, stream>>>(A, ptr_col, adj_col, eps, l,
        Wt_hi + (size_t)l * HD * HD, Wt_lo + (size_t)l * HD * HD,
        b1 + (size_t)l * HD, Z1, st);
    scale_shift_k<<<1, 128, 0, stream>>>(st, bn1_g + (size_t)l * HD, bn1_b + (size_t)l * HD);
    gemm2_k<<<GBLK, 512, 0, stream>>>(Z1, st + 256,
        Wt_hi + (size_t)(NL + l) * HD * HD, Wt_lo + (size_t)(NL + l) * HD * HD,
        b2 + (size_t)l * HD, Z2, st + 512);
    scale_shift_k<<<1, 128, 0, stream>>>(st + 512, bn_g + (size_t)l * HD, bn_b + (size_t)l * HD);
  }

  // ---- pooled head (BN of layer 4 fused, no relu) ----
  pool_final_k<<<NG, 128, 0, stream>>>(Z2, stats + 4 * 1024 + 768, gp,
      cw1, cb1, cw2, cb2, out);
}

// Round 5
// 1371.150 us; speedup vs baseline: 2.1792x; 1.1394x over previous
//
#include <hip/hip_runtime.h>
#include <cstdint>

#define NN 300000
#define NE 600000
#define HD 128
#define NL 5
#define NG 8192
#define AVOC 128
#define BVOC 8
#define NAF 9
#define NBF 3
#define BN_EPS 1e-5f

#define SCAN_B 2048
#define SCAN_NB ((NN + SCAN_B - 1) / SCAN_B)   // 147

#define G1ROWS 128
#define G1BLK ((NN + G1ROWS - 1) / G1ROWS)     // 2344
#define GBM 256
#define GBLK ((NN + GBM - 1) / GBM)            // 1172

typedef unsigned short u16;
typedef unsigned int u32;
typedef __attribute__((ext_vector_type(8))) short bf16x8;
typedef __attribute__((ext_vector_type(4))) float f32x4;

static __device__ __forceinline__ void atomAddF(float* p, float v) { unsafeAtomicAdd(p, v); }

static __device__ __forceinline__ float bf2f(u16 v) {
  union { u32 u; float f; } c; c.u = ((u32)v) << 16; return c.f;
}
static __device__ __forceinline__ u16 f2bf(float f) {
  union { float f; u32 u; } c; c.f = f;
  u32 u = c.u;
  return (u16)((u + 0x7FFFu + ((u >> 16) & 1u)) >> 16);  // RNE
}
static __device__ __forceinline__ u32 cvtpk(float a, float b) {
  u32 r;
  asm("v_cvt_pk_bf16_f32 %0, %1, %2" : "=v"(r) : "v"(a), "v"(b));
  return r;  // lo16 = bf16(a), hi16 = bf16(b), RNE
}
static __device__ __forceinline__ void unp8(uint4 p, float* v) {
  v[0] = bf2f((u16)(p.x & 0xffff)); v[1] = bf2f((u16)(p.x >> 16));
  v[2] = bf2f((u16)(p.y & 0xffff)); v[3] = bf2f((u16)(p.y >> 16));
  v[4] = bf2f((u16)(p.z & 0xffff)); v[5] = bf2f((u16)(p.z >> 16));
  v[6] = bf2f((u16)(p.w & 0xffff)); v[7] = bf2f((u16)(p.w >> 16));
}
static __device__ __forceinline__ uint4 pk8(const float* v) {
  uint4 p;
  p.x = ((u32)f2bf(v[1]) << 16) | f2bf(v[0]);
  p.y = ((u32)f2bf(v[3]) << 16) | f2bf(v[2]);
  p.z = ((u32)f2bf(v[5]) << 16) | f2bf(v[4]);
  p.w = ((u32)f2bf(v[7]) << 16) | f2bf(v[6]);
  return p;
}

// split fp32[8] -> hi bf16x8 + lo bf16x8  (hi+lo represents v to ~2^-17 rel)
static __device__ __forceinline__ void split8(const float* v, bf16x8& hi, bf16x8& lo) {
  union { u32 u[4]; bf16x8 h; } H, L;
  H.u[0] = cvtpk(v[0], v[1]); H.u[1] = cvtpk(v[2], v[3]);
  H.u[2] = cvtpk(v[4], v[5]); H.u[3] = cvtpk(v[6], v[7]);
  float r[8];
  r[0] = bf2f((u16)(H.u[0] & 0xffff)); r[1] = bf2f((u16)(H.u[0] >> 16));
  r[2] = bf2f((u16)(H.u[1] & 0xffff)); r[3] = bf2f((u16)(H.u[1] >> 16));
  r[4] = bf2f((u16)(H.u[2] & 0xffff)); r[5] = bf2f((u16)(H.u[2] >> 16));
  r[6] = bf2f((u16)(H.u[3] & 0xffff)); r[7] = bf2f((u16)(H.u[3] >> 16));
  L.u[0] = cvtpk(v[0] - r[0], v[1] - r[1]); L.u[1] = cvtpk(v[2] - r[2], v[3] - r[3]);
  L.u[2] = cvtpk(v[4] - r[4], v[5] - r[5]); L.u[3] = cvtpk(v[6] - r[6], v[7] - r[7]);
  hi = H.h; lo = L.h;
}

// ================= CSR construction =================
__global__ __launch_bounds__(256) void count_k(const int* __restrict__ ei,
    int* __restrict__ cnt_row, int* __restrict__ cnt_col) {
  int e = blockIdx.x * 256 + threadIdx.x;
  if (e >= NE) return;
  atomicAdd(&cnt_row[ei[e]], 1);
  atomicAdd(&cnt_col[ei[NE + e]], 1);
}

__global__ __launch_bounds__(256) void scan_block_k(int* __restrict__ P, int* __restrict__ bsum) {
  __shared__ int s[256];
  int b = blockIdx.x, t = threadIdx.x;
  int base = b * SCAN_B + t * 8;
  int v[8]; int ts = 0;
#pragma unroll
  for (int j = 0; j < 8; j++) { v[j] = (base + j < NN) ? P[base + j] : 0; ts += v[j]; }
  s[t] = ts;
  __syncthreads();
  for (int off = 1; off < 256; off <<= 1) {
    int tmp = 0;
    if (t >= off) tmp = s[t - off];
    __syncthreads();
    if (t >= off) s[t] += tmp;
    __syncthreads();
  }
  if (t == 255) bsum[b] = s[255];
  int run = (t == 0) ? 0 : s[t - 1];
#pragma unroll
  for (int j = 0; j < 8; j++) {
    if (base + j < NN) P[base + j] = run;
    run += v[j];
  }
}

__global__ __launch_bounds__(256) void scan_tops_k(int* __restrict__ bsum, int* __restrict__ totOut) {
  __shared__ int s[256];
  int t = threadIdx.x;
  s[t] = (t < SCAN_NB) ? bsum[t] : 0;
  __syncthreads();
  for (int off = 1; off < 256; off <<= 1) {
    int tmp = 0;
    if (t >= off) tmp = s[t - off];
    __syncthreads();
    if (t >= off) s[t] += tmp;
    __syncthreads();
  }
  if (t < SCAN_NB) bsum[t] = (t == 0) ? 0 : s[t - 1];
  if (t == 255) *totOut = s[255];
}

__global__ __launch_bounds__(256) void scan_add_k(int* __restrict__ P, const int* __restrict__ bsum) {
  int b = blockIdx.x, t = threadIdx.x;
  int off = bsum[b];
  int base = b * SCAN_B + t * 8;
#pragma unroll
  for (int j = 0; j < 8; j++)
    if (base + j < NN) P[base + j] += off;
}

// fill: adjc = combined bond-attr index (u16) in CSR-row order; adj_col = src node ids
__global__ __launch_bounds__(256) void fill_k(const int* __restrict__ ei,
    const int* __restrict__ ea,
    const int* __restrict__ ptr_row, const int* __restrict__ ptr_col,
    int* __restrict__ fillr, int* __restrict__ fillc,
    u16* __restrict__ adjc, int* __restrict__ adj_col) {
  int e = blockIdx.x * 256 + threadIdx.x;
  if (e >= NE) return;
  int r = ei[e], c = ei[NE + e];
  int a0 = ea[e * 3 + 0], a1 = ea[e * 3 + 1], a2 = ea[e * 3 + 2];
  int p1 = atomicAdd(&fillr[r], 1);
  adjc[ptr_row[r] + p1] = (u16)(a0 + (a1 << 3) + (a2 << 6));
  int p2 = atomicAdd(&fillc[c], 1);
  adj_col[ptr_col[c] + p2] = r;
}

__global__ __launch_bounds__(256) void inv_k(const int* __restrict__ ptr_row, float* __restrict__ inv) {
  int n = blockIdx.x * 256 + threadIdx.x;
  if (n < NN) inv[n] = 1.0f / ((float)(ptr_row[n + 1] - ptr_row[n]) + 1.0f);
}

__global__ __launch_bounds__(256) void gp_k(const int* __restrict__ batch, int* __restrict__ gp) {
  int g = blockIdx.x * 256 + threadIdx.x;
  if (g > NG) return;
  int lo = 0, hi = NN;
  while (lo < hi) { int mid = (lo + hi) >> 1; if (batch[mid] < g) lo = mid + 1; else hi = mid; }
  gp[g] = lo;
}

// W split/transpose: Wt[m][c][k] = bf16_hi/lo of W_m[k][c];  m<5 -> w1[m], else w2[m-5]
__global__ __launch_bounds__(256) void wsplit_k(const float* __restrict__ w1,
    const float* __restrict__ w2, u16* __restrict__ Wt_hi, u16* __restrict__ Wt_lo) {
  int m = blockIdx.x;
  const float* W = (m < NL) ? (w1 + (size_t)m * HD * HD) : (w2 + (size_t)(m - NL) * HD * HD);
  int t = threadIdx.x;
  for (int p = 0; p < 64; p++) {
    int o = p * 256 + t;            // linear over [c][k]
    int c = o >> 7, k = o & 127;
    float w = W[k * HD + c];
    u16 hi = f2bf(w);
    float lo = w - bf2f(hi);
    Wt_hi[(size_t)m * HD * HD + o] = hi;
    Wt_lo[(size_t)m * HD * HD + o] = f2bf(lo);
  }
}

// combined bond table: cmb[l][c][ch] = emb0[c&7] + emb1[(c>>3)&7] + emb2[c>>6]  (fp32, same add order)
__global__ __launch_bounds__(128) void cmb_k(const float* __restrict__ bond_emb,
    float* __restrict__ cmb) {
  int b = blockIdx.x;                 // l*512 + c
  int l = b >> 9, c = b & 511;
  int t = threadIdx.x;
  const float* be = bond_emb + (size_t)l * NBF * BVOC * HD;
  float v = be[(c & 7) * HD + t] + be[(BVOC + ((c >> 3) & 7)) * HD + t]
          + be[(2 * BVOC + (c >> 6)) * HD + t];
  cmb[(size_t)b * HD + t] = v;
}

// ================= model kernels =================

// bond + h_in via precomputed cmb table + CSR-ordered adjc (u16).
// Fused with either the atom encoder (ENC, layer 0) or prev layer's BN+relu.
template<bool ENC>
__global__ __launch_bounds__(256) void bond_k(
    const float* __restrict__ cmb, const int* __restrict__ ptr_row,
    const u16* __restrict__ adjc, const float* __restrict__ inv,
    const int* __restrict__ x, const float* __restrict__ emb,
    const u16* __restrict__ Z2, const float* __restrict__ ss,
    u16* __restrict__ A) {
  __shared__ int sx[16 * NAF];
  int t = threadIdx.x;
  int nb = blockIdx.x * 16;
  int n = nb + (t >> 4);
  int c8 = t & 15;
  if constexpr (ENC) {
    if (t < 16 * NAF && nb * NAF + t < NN * NAF) sx[t] = x[nb * NAF + t];
    __syncthreads();
  }
  if (n >= NN) return;
  int beg = ptr_row[n], end = ptr_row[n + 1];
  float acc[8] = {0.f, 0.f, 0.f, 0.f, 0.f, 0.f, 0.f, 0.f};
  if (beg < end) {
    int c = adjc[beg];
    for (int i = beg; i < end; i++) {
      const float* p = cmb + ((size_t)c << 7) + c8 * 8;
      float4 x0 = *(const float4*)p;
      float4 x1 = *(const float4*)(p + 4);
      if (i + 1 < end) c = adjc[i + 1];     // break index->data chain
      acc[0] += x0.x; acc[1] += x0.y; acc[2] += x0.z; acc[3] += x0.w;
      acc[4] += x1.x; acc[5] += x1.y; acc[6] += x1.z; acc[7] += x1.w;
    }
  }
  float h[8];
  if constexpr (ENC) {
#pragma unroll
    for (int j = 0; j < 8; j++) h[j] = 0.f;
#pragma unroll
    for (int f = 0; f < NAF; f++) {
      int v = sx[(t >> 4) * NAF + f];
      const float* e = emb + ((size_t)(f * AVOC + v)) * HD + c8 * 8;
      float4 e0 = *(const float4*)e;
      float4 e1 = *(const float4*)(e + 4);
      h[0] += e0.x; h[1] += e0.y; h[2] += e0.z; h[3] += e0.w;
      h[4] += e1.x; h[5] += e1.y; h[6] += e1.z; h[7] += e1.w;
    }
  } else {
    uint4 p = *(const uint4*)(Z2 + (size_t)n * HD + c8 * 8);
    unp8(p, h);
#pragma unroll
    for (int j = 0; j < 8; j++)
      h[j] = fmaxf(fmaf(h[j], ss[c8 * 8 + j], ss[128 + c8 * 8 + j]), 0.f);
  }
  float iv = inv[n];
#pragma unroll
  for (int j = 0; j < 8; j++) h[j] = fmaf(acc[j], iv, h[j]);
  *(uint4*)(A + (size_t)n * HD + c8 * 8) = pk8(h);
}

// ---------------- GEMM1 with fused GIN aggregation (gather hoisted) ----------------
__global__ __launch_bounds__(512, 4) void gemm1_aggr_k(
    const u16* __restrict__ A, const int* __restrict__ ptr_col,
    const int* __restrict__ adj_col, const float* __restrict__ eps, int lyr,
    const u16* __restrict__ Whi, const u16* __restrict__ Wlo,
    const float* __restrict__ bias, u16* __restrict__ Z1,
    float* __restrict__ stats) {
  __shared__ u16 sW[2 * HD * HD];     // 64 KB: hi then lo, [col][k], XOR-swizzled
  const int tid = threadIdx.x;
#pragma unroll
  for (int p = 0; p < 4; p++) {
    int idx = tid + p * 512;
    int col = idx >> 4, k16 = idx & 15;
    uint4 vh = *(const uint4*)(Whi + idx * 8);
    uint4 vl = *(const uint4*)(Wlo + idx * 8);
    int so = (col << 7) + ((k16 << 3) ^ ((col & 7) << 3));
    *(uint4*)(sW + so) = vh;
    *(uint4*)(sW + HD * HD + so) = vl;
  }
  __syncthreads();

  const float se = 1.0f + eps[lyr];
  const int l = tid & 63, w = tid >> 6;
  const int lr = l & 15, lk = l >> 4;
  const int rw = blockIdx.x * G1ROWS + w * 16;  // wave's 16 rows
  const int gr = rw + lr;                       // this lane's row
  const int kb0 = lk * 8;                       // lane's col base within each 32-chunk

  float z[4][8];
#pragma unroll
  for (int ks = 0; ks < 4; ks++)
#pragma unroll
    for (int j = 0; j < 8; j++) z[ks][j] = 0.f;

  if (gr < NN) {
    const u16* ap = A + (size_t)gr * HD + kb0;
    uint4 s0 = *(const uint4*)(ap);
    uint4 s1 = *(const uint4*)(ap + 32);
    uint4 s2 = *(const uint4*)(ap + 64);
    uint4 s3 = *(const uint4*)(ap + 96);
    int beg = ptr_col[gr], end = ptr_col[gr + 1];
    {
      float v[8];
      unp8(s0, v);
#pragma unroll
      for (int j = 0; j < 8; j++) z[0][j] = v[j] * se;
      unp8(s1, v);
#pragma unroll
      for (int j = 0; j < 8; j++) z[1][j] = v[j] * se;
      unp8(s2, v);
#pragma unroll
      for (int j = 0; j < 8; j++) z[2][j] = v[j] * se;
      unp8(s3, v);
#pragma unroll
      for (int j = 0; j < 8; j++) z[3][j] = v[j] * se;
    }
    if (beg < end) {
      int src = adj_col[beg];
      for (int e = beg; e < end; e++) {
        const u16* sp = A + (size_t)src * HD + kb0;
        uint4 q0 = *(const uint4*)(sp);
        uint4 q1 = *(const uint4*)(sp + 32);
        uint4 q2 = *(const uint4*)(sp + 64);
        uint4 q3 = *(const uint4*)(sp + 96);
        if (e + 1 < end) src = adj_col[e + 1];  // break index->data chain
        float u[8];
        unp8(q0, u);
#pragma unroll
        for (int j = 0; j < 8; j++) z[0][j] += u[j];
        unp8(q1, u);
#pragma unroll
        for (int j = 0; j < 8; j++) z[1][j] += u[j];
        unp8(q2, u);
#pragma unroll
        for (int j = 0; j < 8; j++) z[2][j] += u[j];
        unp8(q3, u);
#pragma unroll
        for (int j = 0; j < 8; j++) z[3][j] += u[j];
      }
    }
  }

  bf16x8 ah[4], al[4];
#pragma unroll
  for (int ks = 0; ks < 4; ks++) split8(z[ks], ah[ks], al[ks]);

  f32x4 acc[8];
#pragma unroll
  for (int jt = 0; jt < 8; jt++) acc[jt] = (f32x4){0.f, 0.f, 0.f, 0.f};
#pragma unroll
  for (int ks = 0; ks < 4; ks++) {
    const int kb = ks * 32 + kb0;
#pragma unroll
    for (int jt = 0; jt < 8; jt++) {
      int col = jt * 16 + lr;
      int so = (col << 7) + (kb ^ ((col & 7) << 3));
      bf16x8 bh = *(const bf16x8*)(sW + so);
      bf16x8 bl = *(const bf16x8*)(sW + HD * HD + so);
      acc[jt] = __builtin_amdgcn_mfma_f32_16x16x32_bf16(ah[ks], bh, acc[jt], 0, 0, 0);
      acc[jt] = __builtin_amdgcn_mfma_f32_16x16x32_bf16(al[ks], bh, acc[jt], 0, 0, 0);
      acc[jt] = __builtin_amdgcn_mfma_f32_16x16x32_bf16(ah[ks], bl, acc[jt], 0, 0, 0);
    }
  }

  // epilogue: +bias, BN stats (fp32 pre-rounding), packed bf16 stores
  float bb[8];
#pragma unroll
  for (int jt = 0; jt < 8; jt++) bb[jt] = bias[jt * 16 + lr];
  float cs[8], cq[8];
#pragma unroll
  for (int jt = 0; jt < 8; jt++) { cs[jt] = 0.f; cq[jt] = 0.f; }
#pragma unroll
  for (int j = 0; j < 4; j++) {
    int gr2 = rw + lk * 4 + j;
    bool ok = gr2 < NN;
#pragma unroll
    for (int jt = 0; jt < 8; jt++) {
      float o = acc[jt][j] + bb[jt];
      if (ok) { cs[jt] += o; cq[jt] += o * o; }
      float on = __shfl_xor(o, 1);
      u32 pw = cvtpk(o, on);
      if (ok && !(l & 1))
        *(u32*)(Z1 + (size_t)gr2 * HD + jt * 16 + lr) = pw;
    }
  }
#pragma unroll
  for (int jt = 0; jt < 8; jt++) {
    cs[jt] += __shfl_xor(cs[jt], 16); cs[jt] += __shfl_xor(cs[jt], 32);
    cq[jt] += __shfl_xor(cq[jt], 16); cq[jt] += __shfl_xor(cq[jt], 32);
  }
  __syncthreads();
  float* sS = (float*)sW;
  if (lk == 0) {
#pragma unroll
    for (int jt = 0; jt < 8; jt++) {
      sS[w * HD + jt * 16 + lr] = cs[jt];
      sS[1024 + w * HD + jt * 16 + lr] = cq[jt];
    }
  }
  __syncthreads();
  if (tid < HD) {
    float s = 0.f, q = 0.f;
#pragma unroll
    for (int g = 0; g < 8; g++) { s += sS[g * HD + tid]; q += sS[1024 + g * HD + tid]; }
    atomAddF(&stats[tid], s);
    atomAddF(&stats[HD + tid], q);
  }
}

// ---------------- GEMM2: relu(BN1(Z1)) @ W2 + b2 -> Z2 bf16 + BN stats ----------------
__global__ __launch_bounds__(512, 4) void gemm2_k(
    const u16* __restrict__ Z1, const float* __restrict__ ss,
    const u16* __restrict__ Whi, const u16* __restrict__ Wlo,
    const float* __restrict__ bias, u16* __restrict__ Z2,
    float* __restrict__ stats) {
  __shared__ u16 sW[2 * HD * HD];
  const int tid = threadIdx.x;
#pragma unroll
  for (int p = 0; p < 4; p++) {
    int idx = tid + p * 512;
    int col = idx >> 4, k16 = idx & 15;
    uint4 vh = *(const uint4*)(Whi + idx * 8);
    uint4 vl = *(const uint4*)(Wlo + idx * 8);
    int so = (col << 7) + ((k16 << 3) ^ ((col & 7) << 3));
    *(uint4*)(sW + so) = vh;
    *(uint4*)(sW + HD * HD + so) = vl;
  }
  __syncthreads();

  const int l = tid & 63, w = tid >> 6;
  const int lr = l & 15, lk = l >> 4;
  const int rw = blockIdx.x * GBM + w * 32;
  f32x4 acc[2][8];
#pragma unroll
  for (int i = 0; i < 2; i++)
#pragma unroll
    for (int j = 0; j < 8; j++) acc[i][j] = (f32x4){0.f, 0.f, 0.f, 0.f};

#pragma unroll
  for (int ks = 0; ks < 4; ks++) {
    const int kb = ks * 32 + lk * 8;
    bf16x8 ah[2], al[2];
#pragma unroll
    for (int i = 0; i < 2; i++) {
      int gr = rw + i * 16 + lr;
      uint4 p = make_uint4(0u, 0u, 0u, 0u);
      if (gr < NN) p = *(const uint4*)(Z1 + (size_t)gr * HD + kb);
      float v[8]; unp8(p, v);
#pragma unroll
      for (int j = 0; j < 8; j++)
        v[j] = fmaxf(fmaf(v[j], ss[kb + j], ss[HD + kb + j]), 0.f);
      split8(v, ah[i], al[i]);
    }
#pragma unroll
    for (int jt = 0; jt < 8; jt++) {
      int col = jt * 16 + lr;
      int so = (col << 7) + (kb ^ ((col & 7) << 3));
      bf16x8 bh = *(const bf16x8*)(sW + so);
      bf16x8 bl = *(const bf16x8*)(sW + HD * HD + so);
#pragma unroll
      for (int i = 0; i < 2; i++) {
        acc[i][jt] = __builtin_amdgcn_mfma_f32_16x16x32_bf16(ah[i], bh, acc[i][jt], 0, 0, 0);
        acc[i][jt] = __builtin_amdgcn_mfma_f32_16x16x32_bf16(al[i], bh, acc[i][jt], 0, 0, 0);
        acc[i][jt] = __builtin_amdgcn_mfma_f32_16x16x32_bf16(ah[i], bl, acc[i][jt], 0, 0, 0);
      }
    }
  }

  float bb[8];
#pragma unroll
  for (int jt = 0; jt < 8; jt++) bb[jt] = bias[jt * 16 + lr];
  float cs[8], cq[8];
#pragma unroll
  for (int jt = 0; jt < 8; jt++) { cs[jt] = 0.f; cq[jt] = 0.f; }
#pragma unroll
  for (int i = 0; i < 2; i++)
#pragma unroll
    for (int j = 0; j < 4; j++) {
      int gr = rw + i * 16 + lk * 4 + j;
      bool ok = gr < NN;
#pragma unroll
      for (int jt = 0; jt < 8; jt++) {
        float o = acc[i][jt][j] + bb[jt];
        if (ok) { cs[jt] += o; cq[jt] += o * o; }
        float on = __shfl_xor(o, 1);
        u32 pw = cvtpk(o, on);
        if (ok && !(l & 1))
          *(u32*)(Z2 + (size_t)gr * HD + jt * 16 + lr) = pw;
      }
    }
#pragma unroll
  for (int jt = 0; jt < 8; jt++) {
    cs[jt] += __shfl_xor(cs[jt], 16); cs[jt] += __shfl_xor(cs[jt], 32);
    cq[jt] += __shfl_xor(cq[jt], 16); cq[jt] += __shfl_xor(cq[jt], 32);
  }
  __syncthreads();
  float* sS = (float*)sW;
  if (lk == 0) {
#pragma unroll
    for (int jt = 0; jt < 8; jt++) {
      sS[w * HD + jt * 16 + lr] = cs[jt];
      sS[1024 + w * HD + jt * 16 + lr] = cq[jt];
    }
  }
  __syncthreads();
  if (tid < HD) {
    float s = 0.f, q = 0.f;
#pragma unroll
    for (int g = 0; g < 8; g++) { s += sS[g * HD + tid]; q += sS[1024 + g * HD + tid]; }
    atomAddF(&stats[tid], s);
    atomAddF(&stats[HD + tid], q);
  }
}

__global__ __launch_bounds__(128) void scale_shift_k(float* __restrict__ stats,
    const float* __restrict__ g, const float* __restrict__ b) {
  int c = threadIdx.x;
  float mean = stats[c] * (1.0f / NN);
  float var = stats[HD + c] * (1.0f / NN) - mean * mean;
  float sc = g[c] * rsqrtf(var + BN_EPS);
  stats[256 + c] = sc;
  stats[384 + c] = fmaf(-mean, sc, b[c]);
}

// fused BN (no relu, layer 4) + global_add_pool + 2-layer MLP head; one block per graph
__global__ __launch_bounds__(128) void pool_final_k(const u16* __restrict__ Z2,
    const float* __restrict__ ss, const int* __restrict__ gp,
    const float* __restrict__ cw1, const float* __restrict__ cb1,
    const float* __restrict__ cw2, const float* __restrict__ cb2,
    float* __restrict__ out) {
  __shared__ float sp[128];
  __shared__ float sh[128];
  int g = blockIdx.x, t = threadIdx.x;
  int beg = gp[g], end = gp[g + 1];
  float acc = 0.f;
  for (int n = beg; n < end; n++) acc += bf2f(Z2[(size_t)n * HD + t]);
  sp[t] = fmaf(acc, ss[t], (float)(end - beg) * ss[128 + t]);
  __syncthreads();
  float h1 = cb1[t];
#pragma unroll
  for (int k = 0; k < HD; k++) h1 = fmaf(sp[k], cw1[k * HD + t], h1);
  h1 = fmaxf(h1, 0.f);
  sh[t] = h1 * cw2[t];
  __syncthreads();
  for (int s = 64; s >= 1; s >>= 1) {
    if (t < s) sh[t] += sh[t + s];
    __syncthreads();
  }
  if (t == 0) out[g] = sh[0] + cb2[0];
}

extern "C" void kernel_launch(void* const* d_in, const int* in_sizes, int n_in,
                              void* d_out, int out_size, void* d_ws, size_t ws_size,
                              hipStream_t stream) {
  const int*   x        = (const int*)d_in[0];
  const int*   ei       = (const int*)d_in[1];
  const int*   ea       = (const int*)d_in[2];
  const int*   batch    = (const int*)d_in[3];
  const float* atom_emb = (const float*)d_in[4];
  const float* bond_emb = (const float*)d_in[5];
  const float* eps      = (const float*)d_in[6];
  const float* w1       = (const float*)d_in[7];
  const float* b1       = (const float*)d_in[8];
  const float* bn1_g    = (const float*)d_in[9];
  const float* bn1_b    = (const float*)d_in[10];
  const float* w2       = (const float*)d_in[11];
  const float* b2       = (const float*)d_in[12];
  const float* bn_g     = (const float*)d_in[13];
  const float* bn_b     = (const float*)d_in[14];
  const float* cw1      = (const float*)d_in[15];
  const float* cb1      = (const float*)d_in[16];
  const float* cw2      = (const float*)d_in[17];
  const float* cb2      = (const float*)d_in[18];
  float* out = (float*)d_out;

  const size_t NH = (size_t)NN * HD;
  float* ws = (float*)d_ws;
  float* stats   = ws;                               // 5*1024 floats
  int*   ptr_row = (int*)(ws + 5 * 1024);            // NN+1
  int*   ptr_col = ptr_row + (NN + 1);               // NN+1
  u16*   adjc    = (u16*)(ptr_col + (NN + 1));       // NE u16 (in old adj_row slot, NE ints)
  int*   adj_col = (int*)adjc + NE;                  // NE
  int*   gp      = adj_col + NE;                     // NG+1
  float* inv     = (float*)(gp + (NG + 1));          // NN
  size_t off = 5 * 1024 + 2 * (size_t)(NN + 1) + 2 * (size_t)NE + (NG + 1) + NN;
  off = (off + 3) & ~(size_t)3;                      // 16B align
  float* B = ws + off;                               // NH fp32 bytes, holds Z1 | Z2 (bf16 halves)
  u16*   Z1 = (u16*)B;                               // lower NH*2 bytes
  u16*   Z2 = Z1 + NH;                               // upper NH*2 bytes
  u16*   A  = (u16*)(B + NH);                        // NH bf16 (h_in)
  u16*   Wt_hi = A + NH;                             // 10 * 128*128 bf16
  u16*   Wt_lo = Wt_hi + 10 * HD * HD;               // 10 * 128*128 bf16
  float* cmb   = (float*)(Wt_lo + 10 * HD * HD);     // 5 * 512 * 128 fp32
  // setup-only temps aliased into B (first written by gemm1_aggr in layer 0)
  int* fillr = (int*)B;
  int* fillc = fillr + NN;
  int* bsums = fillc + NN;                           // SCAN_NB ints

  const int nb_node = (NN + 15) / 16;                        // 18750
  const int nb_e    = (NE + 255) / 256;                      // 2344

  // ---- setup: CSR build + weight split + bond table + graph offsets ----
  hipMemsetAsync(stats, 0, 5 * 1024 * sizeof(float), stream);
  hipMemsetAsync(ptr_row, 0, 2 * (NN + 1) * sizeof(int), stream);
  hipMemsetAsync(fillr, 0, 2 * NN * sizeof(int), stream);

  count_k<<<nb_e, 256, 0, stream>>>(ei, ptr_row, ptr_col);
  scan_block_k<<<SCAN_NB, 256, 0, stream>>>(ptr_row, bsums);
  scan_tops_k<<<1, 256, 0, stream>>>(bsums, &ptr_row[NN]);
  scan_add_k<<<SCAN_NB, 256, 0, stream>>>(ptr_row, bsums);
  scan_block_k<<<SCAN_NB, 256, 0, stream>>>(ptr_col, bsums);
  scan_tops_k<<<1, 256, 0, stream>>>(bsums, &ptr_col[NN]);
  scan_add_k<<<SCAN_NB, 256, 0, stream>>>(ptr_col, bsums);
  inv_k<<<(NN + 255) / 256, 256, 0, stream>>>(ptr_row, inv);
  fill_k<<<nb_e, 256, 0, stream>>>(ei, ea, ptr_row, ptr_col, fillr, fillc, adjc, adj_col);
  wsplit_k<<<2 * NL, 256, 0, stream>>>(w1, w2, Wt_hi, Wt_lo);
  cmb_k<<<NL * 512, 128, 0, stream>>>(bond_emb, cmb);
  gp_k<<<(NG + 1 + 255) / 256, 256, 0, stream>>>(batch, gp);

  // ---- layers ----
  for (int l = 0; l < NL; l++) {
    const float* cl = cmb + (size_t)l * 512 * HD;
    float* st = stats + (size_t)l * 1024;
    if (l == 0) {
      bond_k<true><<<nb_node, 256, 0, stream>>>(cl, ptr_row, adjc, inv,
          x, atom_emb, nullptr, nullptr, A);
    } else {
      bond_k<false><<<nb_node, 256, 0, stream>>>(cl, ptr_row, adjc, inv,
          nullptr, nullptr, Z2, stats + (size_t)(l - 1) * 1024 + 768, A);
    }
    gemm1_aggr_k<<<G1BLK, 512, 0, stream>>>(A, ptr_col, adj_col, eps, l,
        Wt_hi + (size_t)l * HD * HD, Wt_lo + (size_t)l * HD * HD,
        b1 + (size_t)l * HD, Z1, st);
    scale_shift_k<<<1, 128, 0, stream>>>(st, bn1_g + (size_t)l * HD, bn1_b + (size_t)l * HD);
    gemm2_k<<<GBLK, 512, 0, stream>>>(Z1, st + 256,
        Wt_hi + (size_t)(NL + l) * HD * HD, Wt_lo + (size_t)(NL + l) * HD * HD,
        b2 + (size_t)l * HD, Z2, st + 512);
    scale_shift_k<<<1, 128, 0, stream>>>(st + 512, bn_g + (size_t)l * HD, bn_b + (size_t)l * HD);
  }

  // ---- pooled head (BN of layer 4 fused, no relu) ----
  pool_final_k<<<NG, 128, 0, stream>>>(Z2, stats + 4 * 1024 + 768, gp,
      cw1, cb1, cw2, cb2, out);
}